// Round 7
// baseline (261.777 us; speedup 1.0000x reference)
//
#include <hip/hip_runtime.h>

// NonLocalAttentionStack on MI355X.
// Dims: B=1, T=4, C=128, H=W=96, NHEADS=4 (c=32/head), WS=7 (49 cands), PS=3, K=16.
// Pipeline: prep -> ln_stats -> QKV (fp32 GEMM; v output bf16) ->
//           search+topk+softmax (fp32, 16x16 tile, rolling k-band, DPP box-sum) ->
//           fused gather+implicit-conv MFMA GEMM (XCD-swizzled, T14 prefetch,
//           4-wave register-blocked: 72 MFMA per 36 LDS reads = LDS-balanced).

typedef float  f32x4  __attribute__((ext_vector_type(4)));
typedef __bf16 bf16x8 __attribute__((ext_vector_type(8)));
typedef __bf16 bf16x4 __attribute__((ext_vector_type(4)));

__device__ __forceinline__ float dpp_shr1(float x) {  // lane L gets lane L-1 (16-lane rows)
  return __int_as_float(__builtin_amdgcn_update_dpp(0, __float_as_int(x), 0x111, 0xf, 0xf, false));
}
__device__ __forceinline__ float dpp_shl1(float x) {  // lane L gets lane L+1
  return __int_as_float(__builtin_amdgcn_update_dpp(0, __float_as_int(x), 0x101, 0xf, 0xf, false));
}

// ---------------------------------------------------------------------------
// prep: Wt[c][o=384] = {wq|wk|wv}[o][c];  pwt[g][kd][d=9][o=32][i=32] bf16
// ---------------------------------------------------------------------------
__global__ __launch_bounds__(256) void prep_kernel(
    const float* __restrict__ wq, const float* __restrict__ wk, const float* __restrict__ wv,
    const float* __restrict__ pw, float* __restrict__ Wt, __bf16* __restrict__ pwt) {
  int idx = blockIdx.x * 256 + threadIdx.x;
  const int NPW = 4 * 16 * 9 * 32 * 32;  // 589824
  if (idx < NPW) {
    int i  = idx & 31;
    int ol = (idx >> 5) & 31;
    int d  = (idx >> 10) % 9;
    int r  = (idx >> 10) / 9;   // g*16+kd
    int kd = r & 15;
    int g  = r >> 4;
    int o  = g * 32 + ol;
    pwt[idx] = (__bf16)pw[((o * 32 + i) * 16 + kd) * 9 + d];
  } else {
    int widx = idx - NPW;
    if (widx < 128 * 384) {
      int o = widx % 384;
      int c = widx / 384;
      const float* __restrict__ src = (o < 128) ? wq : (o < 256 ? wk : wv);
      Wt[widx] = src[(o & 127) * 128 + c];
    }
  }
}

// ---------------------------------------------------------------------------
// LN stats: per-pixel mean / rsqrt(var+eps).  grid (144,4) x 64 threads.
// ---------------------------------------------------------------------------
__global__ __launch_bounds__(64) void ln_stats_kernel(
    const float* __restrict__ vid, float* __restrict__ mu, float* __restrict__ rs) {
  int pix = blockIdx.x * 64 + threadIdx.x;
  int f = blockIdx.y;
  const float* __restrict__ vp = vid + (size_t)f * 128 * 9216 + pix;
  float s = 0.f, s2 = 0.f;
  #pragma unroll 8
  for (int c = 0; c < 128; ++c) { float x = vp[(size_t)c * 9216]; s += x; s2 += x * x; }
  float m_ = s * (1.f / 128.f);
  float v_ = fmaxf(s2 * (1.f / 128.f) - m_ * m_, 0.f);
  mu[f * 9216 + pix] = m_;
  rs[f * 9216 + pix] = rsqrtf(v_ + 1e-6f);
}

// ---------------------------------------------------------------------------
// QKV GEMM: 128x128 tile, K=128 in 4x32 chunks, 512 threads (8 waves),
// register double-buffered staging.  grid (3, 288); blockIdx.x selects q/k/v.
// q,k: fp32 [t*4+head][pix][c32].  v: bf16 same layout.
// ---------------------------------------------------------------------------
__global__ __launch_bounds__(512) void qkv_gemm_kernel(
    const float* __restrict__ vid, const float* __restrict__ mu, const float* __restrict__ rs,
    const float* __restrict__ lnw, const float* __restrict__ lnb,
    const float* __restrict__ Wt, const float* __restrict__ bq, const float* __restrict__ bk,
    const float* __restrict__ bv, float* __restrict__ qb, float* __restrict__ kb,
    __bf16* __restrict__ vbbf) {
  __shared__ __align__(16) float Xs[32][128];
  __shared__ __align__(16) float Ws[32][128];
  __shared__ float muL[128], rsL[128], lwS[128], lbS[128];
  int tid = threadIdx.x;
  int mt = blockIdx.y;
  int N0 = blockIdx.x * 128;
  int f  = mt / 72;
  int pf = (mt % 72) * 128;

  if (tid < 128) {
    muL[tid] = mu[f * 9216 + pf + tid];
    rsL[tid] = rs[f * 9216 + pf + tid];
  } else if (tid < 256) {
    int t2 = tid - 128;
    lwS[t2] = lnw[t2];
    lbS[t2] = lnb[t2];
  }

  int tx = tid & 15, ty = tid >> 4;   // ty 0..31
  int m0 = ty * 4;
  int sm = tid & 127;                  // staging column
  int sk = tid >> 7;                   // staging row base (0..3)
  float acc[4][8];
  #pragma unroll
  for (int a = 0; a < 4; ++a)
    #pragma unroll
    for (int b = 0; b < 8; ++b) acc[a][b] = 0.f;

  const size_t vbase = (size_t)f * 128 * 9216 + pf;
  float xr[8], wr[8];

  #pragma unroll
  for (int it = 0; it < 8; ++it) {
    int kk = sk + 4 * it;
    xr[it] = vid[vbase + (size_t)kk * 9216 + sm];
    wr[it] = Wt[(size_t)kk * 384 + N0 + sm];
  }
  __syncthreads();
  #pragma unroll
  for (int it = 0; it < 8; ++it) {
    int kk = sk + 4 * it;
    Xs[kk][sm] = (xr[it] - muL[sm]) * rsL[sm] * lwS[kk] + lbS[kk];
    Ws[kk][sm] = wr[it];
  }
  __syncthreads();

  for (int kc = 0; kc < 4; ++kc) {
    if (kc < 3) {
      #pragma unroll
      for (int it = 0; it < 8; ++it) {
        int kk = sk + 4 * it;
        int c = (kc + 1) * 32 + kk;
        xr[it] = vid[vbase + (size_t)c * 9216 + sm];
        wr[it] = Wt[(size_t)c * 384 + N0 + sm];
      }
    }
    #pragma unroll 4
    for (int kk = 0; kk < 32; ++kk) {
      float xa[4], wa[8];
      *(float4*)&xa[0] = *(const float4*)&Xs[kk][m0];
      *(float4*)&wa[0] = *(const float4*)&Ws[kk][tx * 4];
      *(float4*)&wa[4] = *(const float4*)&Ws[kk][64 + tx * 4];
      #pragma unroll
      for (int a = 0; a < 4; ++a)
        #pragma unroll
        for (int b = 0; b < 8; ++b)
          acc[a][b] = fmaf(xa[a], wa[b], acc[a][b]);
    }
    if (kc < 3) {
      __syncthreads();
      #pragma unroll
      for (int it = 0; it < 8; ++it) {
        int kk = sk + 4 * it;
        int c = (kc + 1) * 32 + kk;
        Xs[kk][sm] = (xr[it] - muL[sm]) * rsL[sm] * lwS[c] + lbS[c];
        Ws[kk][sm] = wr[it];
      }
      __syncthreads();
    }
  }

  int sel = blockIdx.x;
  int nlo = tx * 4, nhi = 64 + tx * 4;
  int hlo = nlo >> 5, clo = nlo & 31;
  int hhi = nhi >> 5, chi = nhi & 31;
  const float* __restrict__ bias = (sel == 0) ? bq : (sel == 1 ? bk : bv);
  float4 blo = make_float4(bias[nlo], bias[nlo + 1], bias[nlo + 2], bias[nlo + 3]);
  float4 bhi = make_float4(bias[nhi], bias[nhi + 1], bias[nhi + 2], bias[nhi + 3]);
  size_t base_lo = (size_t)(f * 4 + hlo) * 9216 * 32 + clo;
  size_t base_hi = (size_t)(f * 4 + hhi) * 9216 * 32 + chi;
  if (sel < 2) {
    float* __restrict__ dst = (sel == 0) ? qb : kb;
    #pragma unroll
    for (int a = 0; a < 4; ++a) {
      size_t poff = (size_t)(pf + m0 + a) * 32;
      *(float4*)&dst[base_lo + poff] = make_float4(acc[a][0] + blo.x, acc[a][1] + blo.y,
                                                   acc[a][2] + blo.z, acc[a][3] + blo.w);
      *(float4*)&dst[base_hi + poff] = make_float4(acc[a][4] + bhi.x, acc[a][5] + bhi.y,
                                                   acc[a][6] + bhi.z, acc[a][7] + bhi.w);
    }
  } else {
    #pragma unroll
    for (int a = 0; a < 4; ++a) {
      size_t poff = (size_t)(pf + m0 + a) * 32;
      bf16x4 lo4, hi4;
      lo4[0] = (__bf16)(acc[a][0] + blo.x); lo4[1] = (__bf16)(acc[a][1] + blo.y);
      lo4[2] = (__bf16)(acc[a][2] + blo.z); lo4[3] = (__bf16)(acc[a][3] + blo.w);
      hi4[0] = (__bf16)(acc[a][4] + bhi.x); hi4[1] = (__bf16)(acc[a][5] + bhi.y);
      hi4[2] = (__bf16)(acc[a][6] + bhi.z); hi4[3] = (__bf16)(acc[a][7] + bhi.w);
      *(bf16x4*)&vbbf[base_lo + poff] = lo4;
      *(bf16x4*)&vbbf[base_hi + poff] = hi4;
    }
  }
}

// ---------------------------------------------------------------------------
// search + topk + softmax.  16x16 s-region tile (inner 14x14 queries).
// grid (49, 16), 256 threads, 3 blocks/CU (47 KB LDS).
// ---------------------------------------------------------------------------
__global__ __launch_bounds__(256, 3) void search_kernel(
    const float* __restrict__ qb, const float* __restrict__ kb,
    float* __restrict__ wgtb, int* __restrict__ indb) {
  __shared__ __align__(16) float klds[16 * 22 * 32];   // 45056 B
  __shared__ float slds[2][256];
  int tid = threadIdx.x;
  int th = blockIdx.y;
  int tile = blockIdx.x;
  int iy0 = (tile / 7) * 14, ix0 = (tile % 7) * 14;
  const float* __restrict__ kbase = kb + (size_t)th * 9216 * 32;

  #pragma unroll
  for (int it = 0; it < 11; ++it) {
    int i = it * 256 + tid;
    int r = i / 176, rem = i % 176;
    int col = rem >> 3, c4 = rem & 7;
    int gy = iy0 - 4 + r, gx = ix0 - 4 + col;
    float4 val = make_float4(0.f, 0.f, 0.f, 0.f);
    if ((unsigned)gy < 96u && (unsigned)gx < 96u)
      val = *(const float4*)&kbase[(size_t)(gy * 96 + gx) * 32 + c4 * 4];
    int p = r * 22 + col;
    *(float4*)&klds[p * 32 + ((c4 ^ (p & 7)) << 2)] = val;
  }

  int sy = tid >> 4, sx = tid & 15;
  int qy = iy0 - 1 + sy, qx = ix0 - 1 + sx;
  bool qok = (unsigned)qy < 96u && (unsigned)qx < 96u;
  float4 qv[8];
  #pragma unroll
  for (int j = 0; j < 8; ++j) qv[j] = make_float4(0.f, 0.f, 0.f, 0.f);
  if (qok) {
    const float* __restrict__ qp = qb + ((size_t)th * 9216 + qy * 96 + qx) * 32;
    #pragma unroll
    for (int j = 0; j < 8; ++j) qv[j] = *(const float4*)&qp[j * 4];
  }
  bool inner = (sy >= 1) && (sy <= 14) && (sx >= 1) && (sx <= 14) && qok;

  float tv[16]; int tix[16];
  #pragma unroll
  for (int j = 0; j < 16; ++j) { tv[j] = -3.0e38f; tix[j] = 0; }
  __syncthreads();

  #pragma unroll 1
  for (int dy = 0; dy < 7; ++dy) {
    if (dy > 0) {
      if (tid < 176) {
        int col = tid >> 3, c4 = tid & 7;
        int r = dy + 15;
        int gy = iy0 - 4 + r, gx = ix0 - 4 + col;
        float4 val = make_float4(0.f, 0.f, 0.f, 0.f);
        if ((unsigned)gy < 96u && (unsigned)gx < 96u)
          val = *(const float4*)&kbase[(size_t)(gy * 96 + gx) * 32 + c4 * 4];
        int p = (r & 15) * 22 + col;
        *(float4*)&klds[p * 32 + ((c4 ^ (p & 7)) << 2)] = val;
      }
      __syncthreads();
    }
    #pragma unroll 1
    for (int dx = 0; dx < 7; ++dx) {
      int oi = dy * 7 + dx;
      int p = ((sy + dy) & 15) * 22 + (sx + dx);
      const float* __restrict__ kp = &klds[p * 32];
      int sw = p & 7;
      float sdot = 0.f;
      #pragma unroll
      for (int j = 0; j < 8; ++j) {
        float4 kq = *(const float4*)&kp[(j ^ sw) << 2];
        sdot += qv[j].x * kq.x + qv[j].y * kq.y + qv[j].z * kq.z + qv[j].w * kq.w;
      }
      float h = sdot + dpp_shr1(sdot) + dpp_shl1(sdot);
      slds[oi & 1][tid] = h;
      __syncthreads();
      if (inner) {
        const float* __restrict__ sb = slds[oi & 1];
        float sc = h + sb[tid - 16] + sb[tid + 16];
        float cv = sc; int ci = oi;
        #pragma unroll
        for (int j = 0; j < 16; ++j) {
          bool gt = cv > tv[j];
          float mx = fmaxf(tv[j], cv);
          float mn = fminf(tv[j], cv);
          int nt = gt ? ci : tix[j];
          ci = gt ? tix[j] : ci;
          tv[j] = mx; cv = mn; tix[j] = nt;
        }
      }
    }
  }

  if (inner) {
    float mx = tv[0];
    float e[16], ssum = 0.f;
    #pragma unroll
    for (int j = 0; j < 16; ++j) { e[j] = __expf(tv[j] - mx); ssum += e[j]; }
    float inv = 1.f / ssum;
    size_t base = ((size_t)th * 9216 + qy * 96 + qx) * 16;
    #pragma unroll
    for (int j = 0; j < 4; ++j) {
      *(float4*)&wgtb[base + j * 4] =
          make_float4(e[j*4] * inv, e[j*4+1] * inv, e[j*4+2] * inv, e[j*4+3] * inv);
      *(int4*)&indb[base + j * 4] = make_int4(tix[j*4], tix[j*4+1], tix[j*4+2], tix[j*4+3]);
    }
  }
}

// ---------------------------------------------------------------------------
// fused gather + implicit-conv GEMM, XCD-swizzled, T14 reg-prefetch.
// grid 576 (1D), 256 threads (4 waves).  16x16 px tile, 18x18 halo.
// Wave w computes y-rows 4w..4w+3 x 32 outs: per kd, 18 cached A-frags +
// 18 B-frags feed 72 MFMAs (32 FLOP/LDS-byte, at the LDS-balance point).
// Row stride 36 bf16 (=18 dwords): b128 LDS ops ~conflict-free.
// ---------------------------------------------------------------------------
__global__ __launch_bounds__(256) void proj_kernel(
    const __bf16* __restrict__ vb, const float* __restrict__ wgtb, const int* __restrict__ indb,
    const __bf16* __restrict__ pwt, const float* __restrict__ pb, float* __restrict__ outp) {
  __shared__ __align__(16) __bf16 Alds[324 * 36];
  __shared__ __align__(16) __bf16 Blds[288 * 36];
  int tid = threadIdx.x;
  int bid = blockIdx.x;
  int wg = (bid & 7) * 72 + (bid >> 3);   // XCD-contiguous remap (576 = 8*72)
  int th = wg / 36;                        // f*4+g
  int tile = wg % 36;
  int g = th & 3;
  int ty0 = (tile / 6) * 16, tx0 = (tile % 6) * 16;
  int lane = tid & 63, wid = tid >> 6;     // wid 0..3
  int kg = lane >> 4, lr = lane & 15;

  // gather assignment: px0 = tid (all), px1 = 256+tid (tid<68)
  bool act1 = tid < 68;
  int ry0 = tid / 18, rx0 = tid % 18;
  int py1 = 256 + tid;
  int ry1 = py1 / 18, rx1 = py1 % 18;
  int gy0 = ty0 - 1 + ry0, gx0 = tx0 - 1 + rx0;
  int gy1 = ty0 - 1 + ry1, gx1 = tx0 - 1 + rx1;
  bool inb0 = (unsigned)gy0 < 96u && (unsigned)gx0 < 96u;
  bool inb1 = act1 && (unsigned)gy1 < 96u && (unsigned)gx1 < 96u;
  const __bf16* __restrict__ vbase = vb + (size_t)th * 9216 * 32;
  size_t px0off = inb0 ? (size_t)(gy0 * 96 + gx0) : 0;
  size_t px1off = inb1 ? (size_t)(gy1 * 96 + gx1) : 0;
  const int*   __restrict__ ib0 = indb + ((size_t)th * 9216 + px0off) * 16;
  const float* __restrict__ wb0 = wgtb + ((size_t)th * 9216 + px0off) * 16;
  const int*   __restrict__ ib1 = indb + ((size_t)th * 9216 + px1off) * 16;
  const float* __restrict__ wb1 = wgtb + ((size_t)th * 9216 + px1off) * 16;

  f32x4 acc[4][2];
  #pragma unroll
  for (int a = 0; a < 4; ++a) { acc[a][0] = (f32x4)(0.0f); acc[a][1] = (f32x4)(0.0f); }

  int4 iwi0 = make_int4(0,0,0,0), iwi1 = make_int4(0,0,0,0);
  float4 iww0 = make_float4(0.f,0.f,0.f,0.f), iww1 = make_float4(0.f,0.f,0.f,0.f);
  int4 vr0[4], vr1[4];
  #pragma unroll
  for (int j = 0; j < 4; ++j) { vr0[j] = make_int4(0,0,0,0); vr1[j] = make_int4(0,0,0,0); }
  float wc0 = 0.f, wc1 = 0.f;

  // prologue: iw block 0 + v(kd=0) for both pixels
  if (inb0) {
    iwi0 = *(const int4*)&ib0[0];
    iww0 = *(const float4*)&wb0[0];
    int ny = gy0 + iwi0.x / 7 - 3, nx = gx0 + iwi0.x % 7 - 3;
    if ((unsigned)ny < 96u && (unsigned)nx < 96u) {
      const int4* __restrict__ vp = (const int4*)(vbase + (size_t)(ny * 96 + nx) * 32);
      vr0[0] = vp[0]; vr0[1] = vp[1]; vr0[2] = vp[2]; vr0[3] = vp[3];
    }
    wc0 = iww0.x;
  }
  if (inb1) {
    iwi1 = *(const int4*)&ib1[0];
    iww1 = *(const float4*)&wb1[0];
    int ny = gy1 + iwi1.x / 7 - 3, nx = gx1 + iwi1.x % 7 - 3;
    if ((unsigned)ny < 96u && (unsigned)nx < 96u) {
      const int4* __restrict__ vp = (const int4*)(vbase + (size_t)(ny * 96 + nx) * 32);
      vr1[0] = vp[0]; vr1[1] = vp[1]; vr1[2] = vp[2]; vr1[3] = vp[3];
    }
    wc1 = iww1.x;
  }

  for (int kdb = 0; kdb < 4; ++kdb) {
    #pragma unroll
    for (int kb = 0; kb < 4; ++kb) {
      int kd = kdb * 4 + kb;
      __syncthreads();   // previous MFMA done reading Alds/Blds
      // stage A: weighted bf16 from prefetched regs (px0 always, px1 if act1)
      {
        __bf16 tmp[32];
        #pragma unroll
        for (int wv = 0; wv < 4; ++wv) {
          unsigned uu[4] = {(unsigned)vr0[wv].x, (unsigned)vr0[wv].y,
                            (unsigned)vr0[wv].z, (unsigned)vr0[wv].w};
          #pragma unroll
          for (int j2 = 0; j2 < 4; ++j2) {
            float lo = __uint_as_float(uu[j2] << 16);
            float hi = __uint_as_float(uu[j2] & 0xffff0000u);
            tmp[wv * 8 + j2 * 2]     = (__bf16)(lo * wc0);
            tmp[wv * 8 + j2 * 2 + 1] = (__bf16)(hi * wc0);
          }
        }
        __bf16* dst = &Alds[tid * 36];
        *(int4*)&dst[0]  = *(const int4*)&tmp[0];
        *(int4*)&dst[8]  = *(const int4*)&tmp[8];
        *(int4*)&dst[16] = *(const int4*)&tmp[16];
        *(int4*)&dst[24] = *(const int4*)&tmp[24];
      }
      if (act1) {
        __bf16 tmp[32];
        #pragma unroll
        for (int wv = 0; wv < 4; ++wv) {
          unsigned uu[4] = {(unsigned)vr1[wv].x, (unsigned)vr1[wv].y,
                            (unsigned)vr1[wv].z, (unsigned)vr1[wv].w};
          #pragma unroll
          for (int j2 = 0; j2 < 4; ++j2) {
            float lo = __uint_as_float(uu[j2] << 16);
            float hi = __uint_as_float(uu[j2] & 0xffff0000u);
            tmp[wv * 8 + j2 * 2]     = (__bf16)(lo * wc1);
            tmp[wv * 8 + j2 * 2 + 1] = (__bf16)(hi * wc1);
          }
        }
        __bf16* dst = &Alds[(256 + tid) * 36];
        *(int4*)&dst[0]  = *(const int4*)&tmp[0];
        *(int4*)&dst[8]  = *(const int4*)&tmp[8];
        *(int4*)&dst[16] = *(const int4*)&tmp[16];
        *(int4*)&dst[24] = *(const int4*)&tmp[24];
      }
      // stage B: 1152 int4 tasks over 256 threads
      {
        const __bf16* __restrict__ bsrc = pwt + (size_t)(g * 16 + kd) * 9216;
        #pragma unroll
        for (int itb = 0; itb < 5; ++itb) {
          int i = itb * 256 + tid;
          if (i < 1152) {
            int row = i >> 2, c = i & 3;
            *(int4*)&Blds[row * 36 + c * 8] = *(const int4*)&bsrc[row * 32 + c * 8];
          }
        }
      }
      __syncthreads();
      // T14: prefetch gather for kd+1
      if (kd < 15) {
        int indn0, indn1; float wn0, wn1;
        if (kb == 3) {
          if (inb0) { iwi0 = *(const int4*)&ib0[kd + 1]; iww0 = *(const float4*)&wb0[kd + 1]; }
          if (inb1) { iwi1 = *(const int4*)&ib1[kd + 1]; iww1 = *(const float4*)&wb1[kd + 1]; }
          indn0 = iwi0.x; wn0 = iww0.x;
          indn1 = iwi1.x; wn1 = iww1.x;
        } else {
          indn0 = (kb == 0) ? iwi0.y : (kb == 1) ? iwi0.z : iwi0.w;
          wn0   = (kb == 0) ? iww0.y : (kb == 1) ? iww0.z : iww0.w;
          indn1 = (kb == 0) ? iwi1.y : (kb == 1) ? iwi1.z : iwi1.w;
          wn1   = (kb == 0) ? iww1.y : (kb == 1) ? iww1.z : iww1.w;
        }
        #pragma unroll
        for (int j = 0; j < 4; ++j) { vr0[j] = make_int4(0,0,0,0); vr1[j] = make_int4(0,0,0,0); }
        if (inb0) {
          int ny = gy0 + indn0 / 7 - 3, nx = gx0 + indn0 % 7 - 3;
          if ((unsigned)ny < 96u && (unsigned)nx < 96u) {
            const int4* __restrict__ vp = (const int4*)(vbase + (size_t)(ny * 96 + nx) * 32);
            vr0[0] = vp[0]; vr0[1] = vp[1]; vr0[2] = vp[2]; vr0[3] = vp[3];
          }
        }
        if (inb1) {
          int ny = gy1 + indn1 / 7 - 3, nx = gx1 + indn1 % 7 - 3;
          if ((unsigned)ny < 96u && (unsigned)nx < 96u) {
            const int4* __restrict__ vp = (const int4*)(vbase + (size_t)(ny * 96 + nx) * 32);
            vr1[0] = vp[0]; vr1[1] = vp[1]; vr1[2] = vp[2]; vr1[3] = vp[3];
          }
        }
        wc0 = wn0; wc1 = wn1;
      }
      // cache A-frags: rows wid*4+r (r=0..5), cols lr+dxi (dxi=0..2)
      bf16x8 a[6][3];
      #pragma unroll
      for (int r = 0; r < 6; ++r)
        #pragma unroll
        for (int dxi = 0; dxi < 3; ++dxi)
          a[r][dxi] = *(const bf16x8*)&Alds[((wid * 4 + r) * 18 + lr + dxi) * 36 + kg * 8];
      // MFMA: 9 taps x 4 rows x 2 out-halves, A from register cache
      #pragma unroll
      for (int dy2 = 0; dy2 < 3; ++dy2) {
        #pragma unroll
        for (int dx2 = 0; dx2 < 3; ++dx2) {
          int d = dy2 * 3 + dx2;
          bf16x8 b0 = *(const bf16x8*)&Blds[(d * 32 + lr) * 36 + kg * 8];
          bf16x8 b1 = *(const bf16x8*)&Blds[(d * 32 + 16 + lr) * 36 + kg * 8];
          #pragma unroll
          for (int mt = 0; mt < 4; ++mt) {
            acc[mt][0] = __builtin_amdgcn_mfma_f32_16x16x32_bf16(a[mt + dy2][dx2], b0, acc[mt][0], 0, 0, 0);
            acc[mt][1] = __builtin_amdgcn_mfma_f32_16x16x32_bf16(a[mt + dy2][dx2], b1, acc[mt][1], 0, 0, 0);
          }
        }
      }
    }
  }

  // epilogue: D col = lane&15 -> o, D row = kg*4+j -> pixel x
  int x0 = tx0 + kg * 4;
  int f = th >> 2;
  #pragma unroll
  for (int mt = 0; mt < 4; ++mt) {
    int y = ty0 + wid * 4 + mt;
    #pragma unroll
    for (int nt = 0; nt < 2; ++nt) {
      int o = g * 32 + nt * 16 + lr;
      float bias = pb[o];
      float4 res = make_float4(acc[mt][nt][0] + bias, acc[mt][nt][1] + bias,
                               acc[mt][nt][2] + bias, acc[mt][nt][3] + bias);
      *(float4*)&outp[(size_t)(f * 128 + o) * 9216 + y * 96 + x0] = res;
    }
  }
}

// ---------------------------------------------------------------------------
extern "C" void kernel_launch(void* const* d_in, const int* in_sizes, int n_in,
                              void* d_out, int out_size, void* d_ws, size_t ws_size,
                              hipStream_t stream) {
  const float* vid = (const float*)d_in[0];
  const float* lnw = (const float*)d_in[1];
  const float* lnb = (const float*)d_in[2];
  const float* wq  = (const float*)d_in[3];
  const float* bq  = (const float*)d_in[4];
  const float* wk  = (const float*)d_in[5];
  const float* bk  = (const float*)d_in[6];
  const float* wv_ = (const float*)d_in[7];
  const float* bv  = (const float*)d_in[8];
  const float* pw  = (const float*)d_in[9];
  const float* pb  = (const float*)d_in[10];
  float* outp = (float*)d_out;

  const size_t SZ_T  = (size_t)16 * 9216 * 32 * 4;     // q/k fp32 each
  const size_t SZ_TB = (size_t)16 * 9216 * 32 * 2;     // v bf16
  const size_t SZ_W  = (size_t)16 * 9216 * 16 * 4;     // wgt / ind
  const size_t SZ_WT = 128 * 384 * 4;
  const size_t SZ_PW = (size_t)4 * 16 * 9 * 32 * 32 * 2;
  const size_t SZ_MU = (size_t)4 * 9216 * 4;

  char* p = (char*)d_ws;
  float* qb = (float*)p;        p += SZ_T;
  float* kb = (float*)p;        p += SZ_T;
  __bf16* vbbf = (__bf16*)p;    p += SZ_TB;
  float* wgtb = (float*)p;      p += SZ_W;
  int*   indb = (int*)p;        p += SZ_W;
  float* Wt = (float*)p;        p += SZ_WT;
  __bf16* pwt = (__bf16*)p;     p += SZ_PW;
  float* mu = (float*)p;        p += SZ_MU;
  float* rs = (float*)p;

  prep_kernel<<<2496, 256, 0, stream>>>(wq, wk, wv_, pw, Wt, pwt);
  ln_stats_kernel<<<dim3(144, 4), 64, 0, stream>>>(vid, mu, rs);
  qkv_gemm_kernel<<<dim3(3, 288), 512, 0, stream>>>(vid, mu, rs, lnw, lnb, Wt, bq, bk, bv,
                                                    qb, kb, vbbf);
  search_kernel<<<dim3(49, 16), 256, 0, stream>>>(qb, kb, wgtb, indb);
  proj_kernel<<<576, 256, 0, stream>>>(vbbf, wgtb, indb, pwt, pb, outp);
}

// Round 8
// 245.592 us; speedup vs baseline: 1.0659x; 1.0659x over previous
//
#include <hip/hip_runtime.h>

// NonLocalAttentionStack on MI355X.
// Dims: B=1, T=4, C=128, H=W=96, NHEADS=4 (c=32/head), WS=7 (49 cands), PS=3, K=16.
// Pipeline: prep -> ln_stats -> QKV (fp32 GEMM; v output bf16) ->
//           search+topk+softmax (fp32, 16x16 tile, rolling k-band, DPP box-sum) ->
//           fused gather+implicit-conv MFMA GEMM (XCD-swizzled, T14 prefetch,
//           8 waves x 2 rows, stride-36 LDS, dx-major A row-cache).

typedef float  f32x4  __attribute__((ext_vector_type(4)));
typedef __bf16 bf16x8 __attribute__((ext_vector_type(8)));
typedef __bf16 bf16x4 __attribute__((ext_vector_type(4)));

__device__ __forceinline__ float dpp_shr1(float x) {  // lane L gets lane L-1 (16-lane rows)
  return __int_as_float(__builtin_amdgcn_update_dpp(0, __float_as_int(x), 0x111, 0xf, 0xf, false));
}
__device__ __forceinline__ float dpp_shl1(float x) {  // lane L gets lane L+1
  return __int_as_float(__builtin_amdgcn_update_dpp(0, __float_as_int(x), 0x101, 0xf, 0xf, false));
}

// ---------------------------------------------------------------------------
// prep: Wt[c][o=384] = {wq|wk|wv}[o][c];  pwt[g][kd][d=9][o=32][i=32] bf16
// ---------------------------------------------------------------------------
__global__ __launch_bounds__(256) void prep_kernel(
    const float* __restrict__ wq, const float* __restrict__ wk, const float* __restrict__ wv,
    const float* __restrict__ pw, float* __restrict__ Wt, __bf16* __restrict__ pwt) {
  int idx = blockIdx.x * 256 + threadIdx.x;
  const int NPW = 4 * 16 * 9 * 32 * 32;  // 589824
  if (idx < NPW) {
    int i  = idx & 31;
    int ol = (idx >> 5) & 31;
    int d  = (idx >> 10) % 9;
    int r  = (idx >> 10) / 9;   // g*16+kd
    int kd = r & 15;
    int g  = r >> 4;
    int o  = g * 32 + ol;
    pwt[idx] = (__bf16)pw[((o * 32 + i) * 16 + kd) * 9 + d];
  } else {
    int widx = idx - NPW;
    if (widx < 128 * 384) {
      int o = widx % 384;
      int c = widx / 384;
      const float* __restrict__ src = (o < 128) ? wq : (o < 256 ? wk : wv);
      Wt[widx] = src[(o & 127) * 128 + c];
    }
  }
}

// ---------------------------------------------------------------------------
// LN stats: per-pixel mean / rsqrt(var+eps).  grid (144,4) x 64 threads.
// ---------------------------------------------------------------------------
__global__ __launch_bounds__(64) void ln_stats_kernel(
    const float* __restrict__ vid, float* __restrict__ mu, float* __restrict__ rs) {
  int pix = blockIdx.x * 64 + threadIdx.x;
  int f = blockIdx.y;
  const float* __restrict__ vp = vid + (size_t)f * 128 * 9216 + pix;
  float s = 0.f, s2 = 0.f;
  #pragma unroll 8
  for (int c = 0; c < 128; ++c) { float x = vp[(size_t)c * 9216]; s += x; s2 += x * x; }
  float m_ = s * (1.f / 128.f);
  float v_ = fmaxf(s2 * (1.f / 128.f) - m_ * m_, 0.f);
  mu[f * 9216 + pix] = m_;
  rs[f * 9216 + pix] = rsqrtf(v_ + 1e-6f);
}

// ---------------------------------------------------------------------------
// QKV GEMM: 128x128 tile, K=128 in 4x32 chunks, 512 threads (8 waves),
// register double-buffered staging.  grid (3, 288); blockIdx.x selects q/k/v.
// q,k: fp32 [t*4+head][pix][c32].  v: bf16 same layout.
// ---------------------------------------------------------------------------
__global__ __launch_bounds__(512) void qkv_gemm_kernel(
    const float* __restrict__ vid, const float* __restrict__ mu, const float* __restrict__ rs,
    const float* __restrict__ lnw, const float* __restrict__ lnb,
    const float* __restrict__ Wt, const float* __restrict__ bq, const float* __restrict__ bk,
    const float* __restrict__ bv, float* __restrict__ qb, float* __restrict__ kb,
    __bf16* __restrict__ vbbf) {
  __shared__ __align__(16) float Xs[32][128];
  __shared__ __align__(16) float Ws[32][128];
  __shared__ float muL[128], rsL[128], lwS[128], lbS[128];
  int tid = threadIdx.x;
  int mt = blockIdx.y;
  int N0 = blockIdx.x * 128;
  int f  = mt / 72;
  int pf = (mt % 72) * 128;

  if (tid < 128) {
    muL[tid] = mu[f * 9216 + pf + tid];
    rsL[tid] = rs[f * 9216 + pf + tid];
  } else if (tid < 256) {
    int t2 = tid - 128;
    lwS[t2] = lnw[t2];
    lbS[t2] = lnb[t2];
  }

  int tx = tid & 15, ty = tid >> 4;   // ty 0..31
  int m0 = ty * 4;
  int sm = tid & 127;                  // staging column
  int sk = tid >> 7;                   // staging row base (0..3)
  float acc[4][8];
  #pragma unroll
  for (int a = 0; a < 4; ++a)
    #pragma unroll
    for (int b = 0; b < 8; ++b) acc[a][b] = 0.f;

  const size_t vbase = (size_t)f * 128 * 9216 + pf;
  float xr[8], wr[8];

  #pragma unroll
  for (int it = 0; it < 8; ++it) {
    int kk = sk + 4 * it;
    xr[it] = vid[vbase + (size_t)kk * 9216 + sm];
    wr[it] = Wt[(size_t)kk * 384 + N0 + sm];
  }
  __syncthreads();
  #pragma unroll
  for (int it = 0; it < 8; ++it) {
    int kk = sk + 4 * it;
    Xs[kk][sm] = (xr[it] - muL[sm]) * rsL[sm] * lwS[kk] + lbS[kk];
    Ws[kk][sm] = wr[it];
  }
  __syncthreads();

  for (int kc = 0; kc < 4; ++kc) {
    if (kc < 3) {
      #pragma unroll
      for (int it = 0; it < 8; ++it) {
        int kk = sk + 4 * it;
        int c = (kc + 1) * 32 + kk;
        xr[it] = vid[vbase + (size_t)c * 9216 + sm];
        wr[it] = Wt[(size_t)c * 384 + N0 + sm];
      }
    }
    #pragma unroll 4
    for (int kk = 0; kk < 32; ++kk) {
      float xa[4], wa[8];
      *(float4*)&xa[0] = *(const float4*)&Xs[kk][m0];
      *(float4*)&wa[0] = *(const float4*)&Ws[kk][tx * 4];
      *(float4*)&wa[4] = *(const float4*)&Ws[kk][64 + tx * 4];
      #pragma unroll
      for (int a = 0; a < 4; ++a)
        #pragma unroll
        for (int b = 0; b < 8; ++b)
          acc[a][b] = fmaf(xa[a], wa[b], acc[a][b]);
    }
    if (kc < 3) {
      __syncthreads();
      #pragma unroll
      for (int it = 0; it < 8; ++it) {
        int kk = sk + 4 * it;
        int c = (kc + 1) * 32 + kk;
        Xs[kk][sm] = (xr[it] - muL[sm]) * rsL[sm] * lwS[c] + lbS[c];
        Ws[kk][sm] = wr[it];
      }
      __syncthreads();
    }
  }

  int sel = blockIdx.x;
  int nlo = tx * 4, nhi = 64 + tx * 4;
  int hlo = nlo >> 5, clo = nlo & 31;
  int hhi = nhi >> 5, chi = nhi & 31;
  const float* __restrict__ bias = (sel == 0) ? bq : (sel == 1 ? bk : bv);
  float4 blo = make_float4(bias[nlo], bias[nlo + 1], bias[nlo + 2], bias[nlo + 3]);
  float4 bhi = make_float4(bias[nhi], bias[nhi + 1], bias[nhi + 2], bias[nhi + 3]);
  size_t base_lo = (size_t)(f * 4 + hlo) * 9216 * 32 + clo;
  size_t base_hi = (size_t)(f * 4 + hhi) * 9216 * 32 + chi;
  if (sel < 2) {
    float* __restrict__ dst = (sel == 0) ? qb : kb;
    #pragma unroll
    for (int a = 0; a < 4; ++a) {
      size_t poff = (size_t)(pf + m0 + a) * 32;
      *(float4*)&dst[base_lo + poff] = make_float4(acc[a][0] + blo.x, acc[a][1] + blo.y,
                                                   acc[a][2] + blo.z, acc[a][3] + blo.w);
      *(float4*)&dst[base_hi + poff] = make_float4(acc[a][4] + bhi.x, acc[a][5] + bhi.y,
                                                   acc[a][6] + bhi.z, acc[a][7] + bhi.w);
    }
  } else {
    #pragma unroll
    for (int a = 0; a < 4; ++a) {
      size_t poff = (size_t)(pf + m0 + a) * 32;
      bf16x4 lo4, hi4;
      lo4[0] = (__bf16)(acc[a][0] + blo.x); lo4[1] = (__bf16)(acc[a][1] + blo.y);
      lo4[2] = (__bf16)(acc[a][2] + blo.z); lo4[3] = (__bf16)(acc[a][3] + blo.w);
      hi4[0] = (__bf16)(acc[a][4] + bhi.x); hi4[1] = (__bf16)(acc[a][5] + bhi.y);
      hi4[2] = (__bf16)(acc[a][6] + bhi.z); hi4[3] = (__bf16)(acc[a][7] + bhi.w);
      *(bf16x4*)&vbbf[base_lo + poff] = lo4;
      *(bf16x4*)&vbbf[base_hi + poff] = hi4;
    }
  }
}

// ---------------------------------------------------------------------------
// search + topk + softmax.  16x16 s-region tile (inner 14x14 queries).
// grid (49, 16), 256 threads, 3 blocks/CU (47 KB LDS).
// ---------------------------------------------------------------------------
__global__ __launch_bounds__(256, 3) void search_kernel(
    const float* __restrict__ qb, const float* __restrict__ kb,
    float* __restrict__ wgtb, int* __restrict__ indb) {
  __shared__ __align__(16) float klds[16 * 22 * 32];   // 45056 B
  __shared__ float slds[2][256];
  int tid = threadIdx.x;
  int th = blockIdx.y;
  int tile = blockIdx.x;
  int iy0 = (tile / 7) * 14, ix0 = (tile % 7) * 14;
  const float* __restrict__ kbase = kb + (size_t)th * 9216 * 32;

  #pragma unroll
  for (int it = 0; it < 11; ++it) {
    int i = it * 256 + tid;
    int r = i / 176, rem = i % 176;
    int col = rem >> 3, c4 = rem & 7;
    int gy = iy0 - 4 + r, gx = ix0 - 4 + col;
    float4 val = make_float4(0.f, 0.f, 0.f, 0.f);
    if ((unsigned)gy < 96u && (unsigned)gx < 96u)
      val = *(const float4*)&kbase[(size_t)(gy * 96 + gx) * 32 + c4 * 4];
    int p = r * 22 + col;
    *(float4*)&klds[p * 32 + ((c4 ^ (p & 7)) << 2)] = val;
  }

  int sy = tid >> 4, sx = tid & 15;
  int qy = iy0 - 1 + sy, qx = ix0 - 1 + sx;
  bool qok = (unsigned)qy < 96u && (unsigned)qx < 96u;
  float4 qv[8];
  #pragma unroll
  for (int j = 0; j < 8; ++j) qv[j] = make_float4(0.f, 0.f, 0.f, 0.f);
  if (qok) {
    const float* __restrict__ qp = qb + ((size_t)th * 9216 + qy * 96 + qx) * 32;
    #pragma unroll
    for (int j = 0; j < 8; ++j) qv[j] = *(const float4*)&qp[j * 4];
  }
  bool inner = (sy >= 1) && (sy <= 14) && (sx >= 1) && (sx <= 14) && qok;

  float tv[16]; int tix[16];
  #pragma unroll
  for (int j = 0; j < 16; ++j) { tv[j] = -3.0e38f; tix[j] = 0; }
  __syncthreads();

  #pragma unroll 1
  for (int dy = 0; dy < 7; ++dy) {
    if (dy > 0) {
      if (tid < 176) {
        int col = tid >> 3, c4 = tid & 7;
        int r = dy + 15;
        int gy = iy0 - 4 + r, gx = ix0 - 4 + col;
        float4 val = make_float4(0.f, 0.f, 0.f, 0.f);
        if ((unsigned)gy < 96u && (unsigned)gx < 96u)
          val = *(const float4*)&kbase[(size_t)(gy * 96 + gx) * 32 + c4 * 4];
        int p = (r & 15) * 22 + col;
        *(float4*)&klds[p * 32 + ((c4 ^ (p & 7)) << 2)] = val;
      }
      __syncthreads();
    }
    #pragma unroll 1
    for (int dx = 0; dx < 7; ++dx) {
      int oi = dy * 7 + dx;
      int p = ((sy + dy) & 15) * 22 + (sx + dx);
      const float* __restrict__ kp = &klds[p * 32];
      int sw = p & 7;
      float sdot = 0.f;
      #pragma unroll
      for (int j = 0; j < 8; ++j) {
        float4 kq = *(const float4*)&kp[(j ^ sw) << 2];
        sdot += qv[j].x * kq.x + qv[j].y * kq.y + qv[j].z * kq.z + qv[j].w * kq.w;
      }
      float h = sdot + dpp_shr1(sdot) + dpp_shl1(sdot);
      slds[oi & 1][tid] = h;
      __syncthreads();
      if (inner) {
        const float* __restrict__ sb = slds[oi & 1];
        float sc = h + sb[tid - 16] + sb[tid + 16];
        float cv = sc; int ci = oi;
        #pragma unroll
        for (int j = 0; j < 16; ++j) {
          bool gt = cv > tv[j];
          float mx = fmaxf(tv[j], cv);
          float mn = fminf(tv[j], cv);
          int nt = gt ? ci : tix[j];
          ci = gt ? tix[j] : ci;
          tv[j] = mx; cv = mn; tix[j] = nt;
        }
      }
    }
  }

  if (inner) {
    float mx = tv[0];
    float e[16], ssum = 0.f;
    #pragma unroll
    for (int j = 0; j < 16; ++j) { e[j] = __expf(tv[j] - mx); ssum += e[j]; }
    float inv = 1.f / ssum;
    size_t base = ((size_t)th * 9216 + qy * 96 + qx) * 16;
    #pragma unroll
    for (int j = 0; j < 4; ++j) {
      *(float4*)&wgtb[base + j * 4] =
          make_float4(e[j*4] * inv, e[j*4+1] * inv, e[j*4+2] * inv, e[j*4+3] * inv);
      *(int4*)&indb[base + j * 4] = make_int4(tix[j*4], tix[j*4+1], tix[j*4+2], tix[j*4+3]);
    }
  }
}

// ---------------------------------------------------------------------------
// fused gather + implicit-conv GEMM, XCD-swizzled, T14 reg-prefetch.
// grid 576 (1D), 512 threads (8 waves x 2 rows).  16x16 px tile, 18x18 halo.
// LDS stride 36 bf16 (conflict-measured fix); dx-major loop with 4-frag A
// row-cache: per wave-kd 12 A + 18 B reads feed 36 MFMAs.
// ---------------------------------------------------------------------------
__global__ __launch_bounds__(512) void proj_kernel(
    const __bf16* __restrict__ vb, const float* __restrict__ wgtb, const int* __restrict__ indb,
    const __bf16* __restrict__ pwt, const float* __restrict__ pb, float* __restrict__ outp) {
  __shared__ __align__(16) __bf16 Alds[324 * 36];
  __shared__ __align__(16) __bf16 Blds[288 * 36];
  int tid = threadIdx.x;
  int bid = blockIdx.x;
  int wg = (bid & 7) * 72 + (bid >> 3);   // XCD-contiguous remap (576 = 8*72)
  int th = wg / 36;                        // f*4+g
  int tile = wg % 36;
  int g = th & 3;
  int ty0 = (tile / 6) * 16, tx0 = (tile % 6) * 16;
  int lane = tid & 63, wid = tid >> 6;     // wid 0..7
  int kg = lane >> 4, lr = lane & 15;

  bool gact = tid < 324;
  int ry = tid / 18, rx = tid % 18;
  int gy = ty0 - 1 + ry, gx = tx0 - 1 + rx;
  bool inb = gact && (unsigned)gy < 96u && (unsigned)gx < 96u;
  const __bf16* __restrict__ vbase = vb + (size_t)th * 9216 * 32;
  size_t pxoff = inb ? (size_t)(gy * 96 + gx) : 0;
  const int*   __restrict__ ibase = indb + ((size_t)th * 9216 + pxoff) * 16;
  const float* __restrict__ wbase = wgtb + ((size_t)th * 9216 + pxoff) * 16;

  f32x4 acc[2][2];
  acc[0][0] = (f32x4)(0.0f); acc[0][1] = (f32x4)(0.0f);
  acc[1][0] = (f32x4)(0.0f); acc[1][1] = (f32x4)(0.0f);

  int4 iw_i = make_int4(0, 0, 0, 0);
  float4 iw_w = make_float4(0.f, 0.f, 0.f, 0.f);
  int4 vr[4];
  vr[0] = vr[1] = vr[2] = vr[3] = make_int4(0, 0, 0, 0);
  float wcur = 0.f;

  if (inb) {
    iw_i = *(const int4*)&ibase[0];
    iw_w = *(const float4*)&wbase[0];
    int ind0 = iw_i.x;
    int ny = gy + ind0 / 7 - 3, nx = gx + ind0 % 7 - 3;
    if ((unsigned)ny < 96u && (unsigned)nx < 96u) {
      const int4* __restrict__ vp = (const int4*)(vbase + (size_t)(ny * 96 + nx) * 32);
      vr[0] = vp[0]; vr[1] = vp[1]; vr[2] = vp[2]; vr[3] = vp[3];
    }
    wcur = iw_w.x;
  }

  for (int kdb = 0; kdb < 4; ++kdb) {
    #pragma unroll
    for (int kb = 0; kb < 4; ++kb) {
      int kd = kdb * 4 + kb;
      __syncthreads();
      if (gact) {
        __bf16 tmp[32];
        #pragma unroll
        for (int wv = 0; wv < 4; ++wv) {
          unsigned uu[4] = {(unsigned)vr[wv].x, (unsigned)vr[wv].y,
                            (unsigned)vr[wv].z, (unsigned)vr[wv].w};
          #pragma unroll
          for (int j2 = 0; j2 < 4; ++j2) {
            float lo = __uint_as_float(uu[j2] << 16);
            float hi = __uint_as_float(uu[j2] & 0xffff0000u);
            tmp[wv * 8 + j2 * 2]     = (__bf16)(lo * wcur);
            tmp[wv * 8 + j2 * 2 + 1] = (__bf16)(hi * wcur);
          }
        }
        __bf16* dst = &Alds[tid * 36];
        *(int4*)&dst[0]  = *(const int4*)&tmp[0];
        *(int4*)&dst[8]  = *(const int4*)&tmp[8];
        *(int4*)&dst[16] = *(const int4*)&tmp[16];
        *(int4*)&dst[24] = *(const int4*)&tmp[24];
      }
      {
        const __bf16* __restrict__ bsrc = pwt + (size_t)(g * 16 + kd) * 9216;
        #pragma unroll
        for (int itb = 0; itb < 3; ++itb) {
          int i = itb * 512 + tid;
          if (i < 1152) {
            int row = i >> 2, c = i & 3;
            *(int4*)&Blds[row * 36 + c * 8] = *(const int4*)&bsrc[row * 32 + c * 8];
          }
        }
      }
      __syncthreads();
      if (kd < 15) {
        int indn; float wn;
        if (kb == 3) {
          if (inb) {
            iw_i = *(const int4*)&ibase[kd + 1];
            iw_w = *(const float4*)&wbase[kd + 1];
          }
          indn = iw_i.x; wn = iw_w.x;
        } else {
          indn = (kb == 0) ? iw_i.y : (kb == 1) ? iw_i.z : iw_i.w;
          wn   = (kb == 0) ? iw_w.y : (kb == 1) ? iw_w.z : iw_w.w;
        }
        vr[0] = vr[1] = vr[2] = vr[3] = make_int4(0, 0, 0, 0);
        if (inb) {
          int ny = gy + indn / 7 - 3, nx = gx + indn % 7 - 3;
          if ((unsigned)ny < 96u && (unsigned)nx < 96u) {
            const int4* __restrict__ vp = (const int4*)(vbase + (size_t)(ny * 96 + nx) * 32);
            vr[0] = vp[0]; vr[1] = vp[1]; vr[2] = vp[2]; vr[3] = vp[3];
          }
        }
        wcur = wn;
      }
      // dx-major MFMA with 4-frag A row-cache: rows wid*2..wid*2+3 at col lr+dx2
      __builtin_amdgcn_s_setprio(1);
      #pragma unroll
      for (int dx2 = 0; dx2 < 3; ++dx2) {
        bf16x8 a[4];
        #pragma unroll
        for (int r = 0; r < 4; ++r)
          a[r] = *(const bf16x8*)&Alds[((wid * 2 + r) * 18 + lr + dx2) * 36 + kg * 8];
        #pragma unroll
        for (int dy2 = 0; dy2 < 3; ++dy2) {
          int d = dy2 * 3 + dx2;
          bf16x8 b0 = *(const bf16x8*)&Blds[(d * 32 + lr) * 36 + kg * 8];
          bf16x8 b1 = *(const bf16x8*)&Blds[(d * 32 + 16 + lr) * 36 + kg * 8];
          acc[0][0] = __builtin_amdgcn_mfma_f32_16x16x32_bf16(a[dy2],     b0, acc[0][0], 0, 0, 0);
          acc[0][1] = __builtin_amdgcn_mfma_f32_16x16x32_bf16(a[dy2],     b1, acc[0][1], 0, 0, 0);
          acc[1][0] = __builtin_amdgcn_mfma_f32_16x16x32_bf16(a[dy2 + 1], b0, acc[1][0], 0, 0, 0);
          acc[1][1] = __builtin_amdgcn_mfma_f32_16x16x32_bf16(a[dy2 + 1], b1, acc[1][1], 0, 0, 0);
        }
      }
      __builtin_amdgcn_s_setprio(0);
    }
  }

  int x0 = tx0 + kg * 4;
  int f = th >> 2;
  #pragma unroll
  for (int mt = 0; mt < 2; ++mt) {
    int y = ty0 + wid * 2 + mt;
    #pragma unroll
    for (int nt = 0; nt < 2; ++nt) {
      int o = g * 32 + nt * 16 + lr;
      float bias = pb[o];
      float4 res = make_float4(acc[mt][nt][0] + bias, acc[mt][nt][1] + bias,
                               acc[mt][nt][2] + bias, acc[mt][nt][3] + bias);
      *(float4*)&outp[(size_t)(f * 128 + o) * 9216 + y * 96 + x0] = res;
    }
  }
}

// ---------------------------------------------------------------------------
extern "C" void kernel_launch(void* const* d_in, const int* in_sizes, int n_in,
                              void* d_out, int out_size, void* d_ws, size_t ws_size,
                              hipStream_t stream) {
  const float* vid = (const float*)d_in[0];
  const float* lnw = (const float*)d_in[1];
  const float* lnb = (const float*)d_in[2];
  const float* wq  = (const float*)d_in[3];
  const float* bq  = (const float*)d_in[4];
  const float* wk  = (const float*)d_in[5];
  const float* bk  = (const float*)d_in[6];
  const float* wv_ = (const float*)d_in[7];
  const float* bv  = (const float*)d_in[8];
  const float* pw  = (const float*)d_in[9];
  const float* pb  = (const float*)d_in[10];
  float* outp = (float*)d_out;

  const size_t SZ_T  = (size_t)16 * 9216 * 32 * 4;     // q/k fp32 each
  const size_t SZ_TB = (size_t)16 * 9216 * 32 * 2;     // v bf16
  const size_t SZ_W  = (size_t)16 * 9216 * 16 * 4;     // wgt / ind
  const size_t SZ_WT = 128 * 384 * 4;
  const size_t SZ_PW = (size_t)4 * 16 * 9 * 32 * 32 * 2;
  const size_t SZ_MU = (size_t)4 * 9216 * 4;

  char* p = (char*)d_ws;
  float* qb = (float*)p;        p += SZ_T;
  float* kb = (float*)p;        p += SZ_T;
  __bf16* vbbf = (__bf16*)p;    p += SZ_TB;
  float* wgtb = (float*)p;      p += SZ_W;
  int*   indb = (int*)p;        p += SZ_W;
  float* Wt = (float*)p;        p += SZ_WT;
  __bf16* pwt = (__bf16*)p;     p += SZ_PW;
  float* mu = (float*)p;        p += SZ_MU;
  float* rs = (float*)p;

  prep_kernel<<<2496, 256, 0, stream>>>(wq, wk, wv_, pw, Wt, pwt);
  ln_stats_kernel<<<dim3(144, 4), 64, 0, stream>>>(vid, mu, rs);
  qkv_gemm_kernel<<<dim3(3, 288), 512, 0, stream>>>(vid, mu, rs, lnw, lnb, Wt, bq, bk, bv,
                                                    qb, kb, vbbf);
  search_kernel<<<dim3(49, 16), 256, 0, stream>>>(qb, kb, wgtb, indb);
  proj_kernel<<<576, 512, 0, stream>>>(vbbf, wgtb, indb, pwt, pb, outp);
}

// Round 9
// 244.732 us; speedup vs baseline: 1.0697x; 1.0035x over previous
//
#include <hip/hip_runtime.h>

// NonLocalAttentionStack on MI355X.
// Dims: B=1, T=4, C=128, H=W=96, NHEADS=4 (c=32/head), WS=7 (49 cands), PS=3, K=16.
// Pipeline: prep -> ln_stats -> QKV (fp32 GEMM; v output bf16) ->
//           search+topk+softmax (fp32, 16x16 tile, rolling k-band, DPP box-sum) ->
//           fused gather+implicit-conv MFMA GEMM (XCD-swizzled, T14 prefetch,
//           round-6 8-wave structure, LDS stride 36 (conflict fix only)).

typedef float  f32x4  __attribute__((ext_vector_type(4)));
typedef __bf16 bf16x8 __attribute__((ext_vector_type(8)));
typedef __bf16 bf16x4 __attribute__((ext_vector_type(4)));

__device__ __forceinline__ float dpp_shr1(float x) {  // lane L gets lane L-1 (16-lane rows)
  return __int_as_float(__builtin_amdgcn_update_dpp(0, __float_as_int(x), 0x111, 0xf, 0xf, false));
}
__device__ __forceinline__ float dpp_shl1(float x) {  // lane L gets lane L+1
  return __int_as_float(__builtin_amdgcn_update_dpp(0, __float_as_int(x), 0x101, 0xf, 0xf, false));
}

// ---------------------------------------------------------------------------
// prep: Wt[c][o=384] = {wq|wk|wv}[o][c];  pwt[g][kd][d=9][o=32][i=32] bf16
// ---------------------------------------------------------------------------
__global__ __launch_bounds__(256) void prep_kernel(
    const float* __restrict__ wq, const float* __restrict__ wk, const float* __restrict__ wv,
    const float* __restrict__ pw, float* __restrict__ Wt, __bf16* __restrict__ pwt) {
  int idx = blockIdx.x * 256 + threadIdx.x;
  const int NPW = 4 * 16 * 9 * 32 * 32;  // 589824
  if (idx < NPW) {
    int i  = idx & 31;
    int ol = (idx >> 5) & 31;
    int d  = (idx >> 10) % 9;
    int r  = (idx >> 10) / 9;   // g*16+kd
    int kd = r & 15;
    int g  = r >> 4;
    int o  = g * 32 + ol;
    pwt[idx] = (__bf16)pw[((o * 32 + i) * 16 + kd) * 9 + d];
  } else {
    int widx = idx - NPW;
    if (widx < 128 * 384) {
      int o = widx % 384;
      int c = widx / 384;
      const float* __restrict__ src = (o < 128) ? wq : (o < 256 ? wk : wv);
      Wt[widx] = src[(o & 127) * 128 + c];
    }
  }
}

// ---------------------------------------------------------------------------
// LN stats: per-pixel mean / rsqrt(var+eps).  grid (144,4) x 64 threads.
// ---------------------------------------------------------------------------
__global__ __launch_bounds__(64) void ln_stats_kernel(
    const float* __restrict__ vid, float* __restrict__ mu, float* __restrict__ rs) {
  int pix = blockIdx.x * 64 + threadIdx.x;
  int f = blockIdx.y;
  const float* __restrict__ vp = vid + (size_t)f * 128 * 9216 + pix;
  float s = 0.f, s2 = 0.f;
  #pragma unroll 8
  for (int c = 0; c < 128; ++c) { float x = vp[(size_t)c * 9216]; s += x; s2 += x * x; }
  float m_ = s * (1.f / 128.f);
  float v_ = fmaxf(s2 * (1.f / 128.f) - m_ * m_, 0.f);
  mu[f * 9216 + pix] = m_;
  rs[f * 9216 + pix] = rsqrtf(v_ + 1e-6f);
}

// ---------------------------------------------------------------------------
// QKV GEMM: 128x128 tile, K=128 in 4x32 chunks, 512 threads (8 waves),
// register double-buffered staging.  grid (3, 288); blockIdx.x selects q/k/v.
// q,k: fp32 [t*4+head][pix][c32].  v: bf16 same layout.
// ---------------------------------------------------------------------------
__global__ __launch_bounds__(512) void qkv_gemm_kernel(
    const float* __restrict__ vid, const float* __restrict__ mu, const float* __restrict__ rs,
    const float* __restrict__ lnw, const float* __restrict__ lnb,
    const float* __restrict__ Wt, const float* __restrict__ bq, const float* __restrict__ bk,
    const float* __restrict__ bv, float* __restrict__ qb, float* __restrict__ kb,
    __bf16* __restrict__ vbbf) {
  __shared__ __align__(16) float Xs[32][128];
  __shared__ __align__(16) float Ws[32][128];
  __shared__ float muL[128], rsL[128], lwS[128], lbS[128];
  int tid = threadIdx.x;
  int mt = blockIdx.y;
  int N0 = blockIdx.x * 128;
  int f  = mt / 72;
  int pf = (mt % 72) * 128;

  if (tid < 128) {
    muL[tid] = mu[f * 9216 + pf + tid];
    rsL[tid] = rs[f * 9216 + pf + tid];
  } else if (tid < 256) {
    int t2 = tid - 128;
    lwS[t2] = lnw[t2];
    lbS[t2] = lnb[t2];
  }

  int tx = tid & 15, ty = tid >> 4;   // ty 0..31
  int m0 = ty * 4;
  int sm = tid & 127;                  // staging column
  int sk = tid >> 7;                   // staging row base (0..3)
  float acc[4][8];
  #pragma unroll
  for (int a = 0; a < 4; ++a)
    #pragma unroll
    for (int b = 0; b < 8; ++b) acc[a][b] = 0.f;

  const size_t vbase = (size_t)f * 128 * 9216 + pf;
  float xr[8], wr[8];

  #pragma unroll
  for (int it = 0; it < 8; ++it) {
    int kk = sk + 4 * it;
    xr[it] = vid[vbase + (size_t)kk * 9216 + sm];
    wr[it] = Wt[(size_t)kk * 384 + N0 + sm];
  }
  __syncthreads();
  #pragma unroll
  for (int it = 0; it < 8; ++it) {
    int kk = sk + 4 * it;
    Xs[kk][sm] = (xr[it] - muL[sm]) * rsL[sm] * lwS[kk] + lbS[kk];
    Ws[kk][sm] = wr[it];
  }
  __syncthreads();

  for (int kc = 0; kc < 4; ++kc) {
    if (kc < 3) {
      #pragma unroll
      for (int it = 0; it < 8; ++it) {
        int kk = sk + 4 * it;
        int c = (kc + 1) * 32 + kk;
        xr[it] = vid[vbase + (size_t)c * 9216 + sm];
        wr[it] = Wt[(size_t)c * 384 + N0 + sm];
      }
    }
    #pragma unroll 4
    for (int kk = 0; kk < 32; ++kk) {
      float xa[4], wa[8];
      *(float4*)&xa[0] = *(const float4*)&Xs[kk][m0];
      *(float4*)&wa[0] = *(const float4*)&Ws[kk][tx * 4];
      *(float4*)&wa[4] = *(const float4*)&Ws[kk][64 + tx * 4];
      #pragma unroll
      for (int a = 0; a < 4; ++a)
        #pragma unroll
        for (int b = 0; b < 8; ++b)
          acc[a][b] = fmaf(xa[a], wa[b], acc[a][b]);
    }
    if (kc < 3) {
      __syncthreads();
      #pragma unroll
      for (int it = 0; it < 8; ++it) {
        int kk = sk + 4 * it;
        int c = (kc + 1) * 32 + kk;
        Xs[kk][sm] = (xr[it] - muL[sm]) * rsL[sm] * lwS[c] + lbS[c];
        Ws[kk][sm] = wr[it];
      }
      __syncthreads();
    }
  }

  int sel = blockIdx.x;
  int nlo = tx * 4, nhi = 64 + tx * 4;
  int hlo = nlo >> 5, clo = nlo & 31;
  int hhi = nhi >> 5, chi = nhi & 31;
  const float* __restrict__ bias = (sel == 0) ? bq : (sel == 1 ? bk : bv);
  float4 blo = make_float4(bias[nlo], bias[nlo + 1], bias[nlo + 2], bias[nlo + 3]);
  float4 bhi = make_float4(bias[nhi], bias[nhi + 1], bias[nhi + 2], bias[nhi + 3]);
  size_t base_lo = (size_t)(f * 4 + hlo) * 9216 * 32 + clo;
  size_t base_hi = (size_t)(f * 4 + hhi) * 9216 * 32 + chi;
  if (sel < 2) {
    float* __restrict__ dst = (sel == 0) ? qb : kb;
    #pragma unroll
    for (int a = 0; a < 4; ++a) {
      size_t poff = (size_t)(pf + m0 + a) * 32;
      *(float4*)&dst[base_lo + poff] = make_float4(acc[a][0] + blo.x, acc[a][1] + blo.y,
                                                   acc[a][2] + blo.z, acc[a][3] + blo.w);
      *(float4*)&dst[base_hi + poff] = make_float4(acc[a][4] + bhi.x, acc[a][5] + bhi.y,
                                                   acc[a][6] + bhi.z, acc[a][7] + bhi.w);
    }
  } else {
    #pragma unroll
    for (int a = 0; a < 4; ++a) {
      size_t poff = (size_t)(pf + m0 + a) * 32;
      bf16x4 lo4, hi4;
      lo4[0] = (__bf16)(acc[a][0] + blo.x); lo4[1] = (__bf16)(acc[a][1] + blo.y);
      lo4[2] = (__bf16)(acc[a][2] + blo.z); lo4[3] = (__bf16)(acc[a][3] + blo.w);
      hi4[0] = (__bf16)(acc[a][4] + bhi.x); hi4[1] = (__bf16)(acc[a][5] + bhi.y);
      hi4[2] = (__bf16)(acc[a][6] + bhi.z); hi4[3] = (__bf16)(acc[a][7] + bhi.w);
      *(bf16x4*)&vbbf[base_lo + poff] = lo4;
      *(bf16x4*)&vbbf[base_hi + poff] = hi4;
    }
  }
}

// ---------------------------------------------------------------------------
// search + topk + softmax.  16x16 s-region tile (inner 14x14 queries).
// grid (49, 16), 256 threads, 3 blocks/CU (47 KB LDS).
// ---------------------------------------------------------------------------
__global__ __launch_bounds__(256, 3) void search_kernel(
    const float* __restrict__ qb, const float* __restrict__ kb,
    float* __restrict__ wgtb, int* __restrict__ indb) {
  __shared__ __align__(16) float klds[16 * 22 * 32];   // 45056 B
  __shared__ float slds[2][256];
  int tid = threadIdx.x;
  int th = blockIdx.y;
  int tile = blockIdx.x;
  int iy0 = (tile / 7) * 14, ix0 = (tile % 7) * 14;
  const float* __restrict__ kbase = kb + (size_t)th * 9216 * 32;

  #pragma unroll
  for (int it = 0; it < 11; ++it) {
    int i = it * 256 + tid;
    int r = i / 176, rem = i % 176;
    int col = rem >> 3, c4 = rem & 7;
    int gy = iy0 - 4 + r, gx = ix0 - 4 + col;
    float4 val = make_float4(0.f, 0.f, 0.f, 0.f);
    if ((unsigned)gy < 96u && (unsigned)gx < 96u)
      val = *(const float4*)&kbase[(size_t)(gy * 96 + gx) * 32 + c4 * 4];
    int p = r * 22 + col;
    *(float4*)&klds[p * 32 + ((c4 ^ (p & 7)) << 2)] = val;
  }

  int sy = tid >> 4, sx = tid & 15;
  int qy = iy0 - 1 + sy, qx = ix0 - 1 + sx;
  bool qok = (unsigned)qy < 96u && (unsigned)qx < 96u;
  float4 qv[8];
  #pragma unroll
  for (int j = 0; j < 8; ++j) qv[j] = make_float4(0.f, 0.f, 0.f, 0.f);
  if (qok) {
    const float* __restrict__ qp = qb + ((size_t)th * 9216 + qy * 96 + qx) * 32;
    #pragma unroll
    for (int j = 0; j < 8; ++j) qv[j] = *(const float4*)&qp[j * 4];
  }
  bool inner = (sy >= 1) && (sy <= 14) && (sx >= 1) && (sx <= 14) && qok;

  float tv[16]; int tix[16];
  #pragma unroll
  for (int j = 0; j < 16; ++j) { tv[j] = -3.0e38f; tix[j] = 0; }
  __syncthreads();

  #pragma unroll 1
  for (int dy = 0; dy < 7; ++dy) {
    if (dy > 0) {
      if (tid < 176) {
        int col = tid >> 3, c4 = tid & 7;
        int r = dy + 15;
        int gy = iy0 - 4 + r, gx = ix0 - 4 + col;
        float4 val = make_float4(0.f, 0.f, 0.f, 0.f);
        if ((unsigned)gy < 96u && (unsigned)gx < 96u)
          val = *(const float4*)&kbase[(size_t)(gy * 96 + gx) * 32 + c4 * 4];
        int p = (r & 15) * 22 + col;
        *(float4*)&klds[p * 32 + ((c4 ^ (p & 7)) << 2)] = val;
      }
      __syncthreads();
    }
    #pragma unroll 1
    for (int dx = 0; dx < 7; ++dx) {
      int oi = dy * 7 + dx;
      int p = ((sy + dy) & 15) * 22 + (sx + dx);
      const float* __restrict__ kp = &klds[p * 32];
      int sw = p & 7;
      float sdot = 0.f;
      #pragma unroll
      for (int j = 0; j < 8; ++j) {
        float4 kq = *(const float4*)&kp[(j ^ sw) << 2];
        sdot += qv[j].x * kq.x + qv[j].y * kq.y + qv[j].z * kq.z + qv[j].w * kq.w;
      }
      float h = sdot + dpp_shr1(sdot) + dpp_shl1(sdot);
      slds[oi & 1][tid] = h;
      __syncthreads();
      if (inner) {
        const float* __restrict__ sb = slds[oi & 1];
        float sc = h + sb[tid - 16] + sb[tid + 16];
        float cv = sc; int ci = oi;
        #pragma unroll
        for (int j = 0; j < 16; ++j) {
          bool gt = cv > tv[j];
          float mx = fmaxf(tv[j], cv);
          float mn = fminf(tv[j], cv);
          int nt = gt ? ci : tix[j];
          ci = gt ? tix[j] : ci;
          tv[j] = mx; cv = mn; tix[j] = nt;
        }
      }
    }
  }

  if (inner) {
    float mx = tv[0];
    float e[16], ssum = 0.f;
    #pragma unroll
    for (int j = 0; j < 16; ++j) { e[j] = __expf(tv[j] - mx); ssum += e[j]; }
    float inv = 1.f / ssum;
    size_t base = ((size_t)th * 9216 + qy * 96 + qx) * 16;
    #pragma unroll
    for (int j = 0; j < 4; ++j) {
      *(float4*)&wgtb[base + j * 4] =
          make_float4(e[j*4] * inv, e[j*4+1] * inv, e[j*4+2] * inv, e[j*4+3] * inv);
      *(int4*)&indb[base + j * 4] = make_int4(tix[j*4], tix[j*4+1], tix[j*4+2], tix[j*4+3]);
    }
  }
}

// ---------------------------------------------------------------------------
// fused gather + implicit-conv GEMM, XCD-swizzled, T14 reg-prefetch.
// grid 576 (1D), 512 threads (8 waves x 2 rows).  16x16 px tile, 18x18 halo.
// Round-6 structure (dy-major, per-tap A reads, no setprio); LDS stride 36
// bf16 — the only change vs round 6 (conflict-measured: 10.2M -> ~1.3M).
// ---------------------------------------------------------------------------
__global__ __launch_bounds__(512) void proj_kernel(
    const __bf16* __restrict__ vb, const float* __restrict__ wgtb, const int* __restrict__ indb,
    const __bf16* __restrict__ pwt, const float* __restrict__ pb, float* __restrict__ outp) {
  __shared__ __align__(16) __bf16 Alds[324 * 36];
  __shared__ __align__(16) __bf16 Blds[288 * 36];
  int tid = threadIdx.x;
  int bid = blockIdx.x;
  int wg = (bid & 7) * 72 + (bid >> 3);   // XCD-contiguous remap (576 = 8*72)
  int th = wg / 36;                        // f*4+g
  int tile = wg % 36;
  int g = th & 3;
  int ty0 = (tile / 6) * 16, tx0 = (tile % 6) * 16;
  int lane = tid & 63, wid = tid >> 6;     // wid 0..7
  int kg = lane >> 4, lr = lane & 15;

  bool gact = tid < 324;
  int ry = tid / 18, rx = tid % 18;
  int gy = ty0 - 1 + ry, gx = tx0 - 1 + rx;
  bool inb = gact && (unsigned)gy < 96u && (unsigned)gx < 96u;
  const __bf16* __restrict__ vbase = vb + (size_t)th * 9216 * 32;
  size_t pxoff = inb ? (size_t)(gy * 96 + gx) : 0;
  const int*   __restrict__ ibase = indb + ((size_t)th * 9216 + pxoff) * 16;
  const float* __restrict__ wbase = wgtb + ((size_t)th * 9216 + pxoff) * 16;

  f32x4 acc[2][2];
  acc[0][0] = (f32x4)(0.0f); acc[0][1] = (f32x4)(0.0f);
  acc[1][0] = (f32x4)(0.0f); acc[1][1] = (f32x4)(0.0f);

  int4 iw_i = make_int4(0, 0, 0, 0);
  float4 iw_w = make_float4(0.f, 0.f, 0.f, 0.f);
  int4 vr[4];
  vr[0] = vr[1] = vr[2] = vr[3] = make_int4(0, 0, 0, 0);
  float wcur = 0.f;

  if (inb) {
    iw_i = *(const int4*)&ibase[0];
    iw_w = *(const float4*)&wbase[0];
    int ind0 = iw_i.x;
    int ny = gy + ind0 / 7 - 3, nx = gx + ind0 % 7 - 3;
    if ((unsigned)ny < 96u && (unsigned)nx < 96u) {
      const int4* __restrict__ vp = (const int4*)(vbase + (size_t)(ny * 96 + nx) * 32);
      vr[0] = vp[0]; vr[1] = vp[1]; vr[2] = vp[2]; vr[3] = vp[3];
    }
    wcur = iw_w.x;
  }

  for (int kdb = 0; kdb < 4; ++kdb) {
    #pragma unroll
    for (int kb = 0; kb < 4; ++kb) {
      int kd = kdb * 4 + kb;
      __syncthreads();
      if (gact) {
        __bf16 tmp[32];
        #pragma unroll
        for (int wv = 0; wv < 4; ++wv) {
          unsigned uu[4] = {(unsigned)vr[wv].x, (unsigned)vr[wv].y,
                            (unsigned)vr[wv].z, (unsigned)vr[wv].w};
          #pragma unroll
          for (int j2 = 0; j2 < 4; ++j2) {
            float lo = __uint_as_float(uu[j2] << 16);
            float hi = __uint_as_float(uu[j2] & 0xffff0000u);
            tmp[wv * 8 + j2 * 2]     = (__bf16)(lo * wcur);
            tmp[wv * 8 + j2 * 2 + 1] = (__bf16)(hi * wcur);
          }
        }
        __bf16* dst = &Alds[tid * 36];
        *(int4*)&dst[0]  = *(const int4*)&tmp[0];
        *(int4*)&dst[8]  = *(const int4*)&tmp[8];
        *(int4*)&dst[16] = *(const int4*)&tmp[16];
        *(int4*)&dst[24] = *(const int4*)&tmp[24];
      }
      {
        const __bf16* __restrict__ bsrc = pwt + (size_t)(g * 16 + kd) * 9216;
        #pragma unroll
        for (int itb = 0; itb < 3; ++itb) {
          int i = itb * 512 + tid;
          if (i < 1152) {
            int row = i >> 2, c = i & 3;
            *(int4*)&Blds[row * 36 + c * 8] = *(const int4*)&bsrc[row * 32 + c * 8];
          }
        }
      }
      __syncthreads();
      if (kd < 15) {
        int indn; float wn;
        if (kb == 3) {
          if (inb) {
            iw_i = *(const int4*)&ibase[kd + 1];
            iw_w = *(const float4*)&wbase[kd + 1];
          }
          indn = iw_i.x; wn = iw_w.x;
        } else {
          indn = (kb == 0) ? iw_i.y : (kb == 1) ? iw_i.z : iw_i.w;
          wn   = (kb == 0) ? iw_w.y : (kb == 1) ? iw_w.z : iw_w.w;
        }
        vr[0] = vr[1] = vr[2] = vr[3] = make_int4(0, 0, 0, 0);
        if (inb) {
          int ny = gy + indn / 7 - 3, nx = gx + indn % 7 - 3;
          if ((unsigned)ny < 96u && (unsigned)nx < 96u) {
            const int4* __restrict__ vp = (const int4*)(vbase + (size_t)(ny * 96 + nx) * 32);
            vr[0] = vp[0]; vr[1] = vp[1]; vr[2] = vp[2]; vr[3] = vp[3];
          }
        }
        wcur = wn;
      }
      #pragma unroll
      for (int d = 0; d < 9; ++d) {
        int dy = d / 3 - 1, dx = d % 3 - 1;
        bf16x8 b0 = *(const bf16x8*)&Blds[(d * 32 + lr) * 36 + kg * 8];
        bf16x8 b1 = *(const bf16x8*)&Blds[(d * 32 + 16 + lr) * 36 + kg * 8];
        #pragma unroll
        for (int mt = 0; mt < 2; ++mt) {
          int ryy = wid * 2 + mt + 1 + dy;
          int rxx = lr + 1 + dx;
          bf16x8 af = *(const bf16x8*)&Alds[(ryy * 18 + rxx) * 36 + kg * 8];
          acc[mt][0] = __builtin_amdgcn_mfma_f32_16x16x32_bf16(af, b0, acc[mt][0], 0, 0, 0);
          acc[mt][1] = __builtin_amdgcn_mfma_f32_16x16x32_bf16(af, b1, acc[mt][1], 0, 0, 0);
        }
      }
    }
  }

  int x0 = tx0 + kg * 4;
  int f = th >> 2;
  #pragma unroll
  for (int mt = 0; mt < 2; ++mt) {
    int y = ty0 + wid * 2 + mt;
    #pragma unroll
    for (int nt = 0; nt < 2; ++nt) {
      int o = g * 32 + nt * 16 + lr;
      float bias = pb[o];
      float4 res = make_float4(acc[mt][nt][0] + bias, acc[mt][nt][1] + bias,
                               acc[mt][nt][2] + bias, acc[mt][nt][3] + bias);
      *(float4*)&outp[(size_t)(f * 128 + o) * 9216 + y * 96 + x0] = res;
    }
  }
}

// ---------------------------------------------------------------------------
extern "C" void kernel_launch(void* const* d_in, const int* in_sizes, int n_in,
                              void* d_out, int out_size, void* d_ws, size_t ws_size,
                              hipStream_t stream) {
  const float* vid = (const float*)d_in[0];
  const float* lnw = (const float*)d_in[1];
  const float* lnb = (const float*)d_in[2];
  const float* wq  = (const float*)d_in[3];
  const float* bq  = (const float*)d_in[4];
  const float* wk  = (const float*)d_in[5];
  const float* bk  = (const float*)d_in[6];
  const float* wv_ = (const float*)d_in[7];
  const float* bv  = (const float*)d_in[8];
  const float* pw  = (const float*)d_in[9];
  const float* pb  = (const float*)d_in[10];
  float* outp = (float*)d_out;

  const size_t SZ_T  = (size_t)16 * 9216 * 32 * 4;     // q/k fp32 each
  const size_t SZ_TB = (size_t)16 * 9216 * 32 * 2;     // v bf16
  const size_t SZ_W  = (size_t)16 * 9216 * 16 * 4;     // wgt / ind
  const size_t SZ_WT = 128 * 384 * 4;
  const size_t SZ_PW = (size_t)4 * 16 * 9 * 32 * 32 * 2;
  const size_t SZ_MU = (size_t)4 * 9216 * 4;

  char* p = (char*)d_ws;
  float* qb = (float*)p;        p += SZ_T;
  float* kb = (float*)p;        p += SZ_T;
  __bf16* vbbf = (__bf16*)p;    p += SZ_TB;
  float* wgtb = (float*)p;      p += SZ_W;
  int*   indb = (int*)p;        p += SZ_W;
  float* Wt = (float*)p;        p += SZ_WT;
  __bf16* pwt = (__bf16*)p;     p += SZ_PW;
  float* mu = (float*)p;        p += SZ_MU;
  float* rs = (float*)p;

  prep_kernel<<<2496, 256, 0, stream>>>(wq, wk, wv_, pw, Wt, pwt);
  ln_stats_kernel<<<dim3(144, 4), 64, 0, stream>>>(vid, mu, rs);
  qkv_gemm_kernel<<<dim3(3, 288), 512, 0, stream>>>(vid, mu, rs, lnw, lnb, Wt, bq, bk, bv,
                                                    qb, kb, vbbf);
  search_kernel<<<dim3(49, 16), 256, 0, stream>>>(qb, kb, wgtb, indb);
  proj_kernel<<<576, 512, 0, stream>>>(vbbf, wgtb, indb, pwt, pb, outp);
}

// Round 10
// 229.440 us; speedup vs baseline: 1.1409x; 1.0666x over previous
//
#include <hip/hip_runtime.h>

// NonLocalAttentionStack on MI355X.
// Dims: B=1, T=4, C=128, H=W=96, NHEADS=4 (c=32/head), WS=7 (49 cands), PS=3, K=16.
// Pipeline: prep -> ln_stats -> QKV (fp32 GEMM; v output bf16) ->
//           search+topk+softmax (fp32, 16x16 tile, rolling k-band, DPP box-sum) ->
//           fused gather+implicit-conv MFMA GEMM (XCD-swizzled, T14 prefetch,
//           8-wave stride-40 structure + dx-major A register cache: 30 LDS
//           reads / 36 MFMAs per wave-kd; 16B-aligned rows).

typedef float  f32x4  __attribute__((ext_vector_type(4)));
typedef __bf16 bf16x8 __attribute__((ext_vector_type(8)));
typedef __bf16 bf16x4 __attribute__((ext_vector_type(4)));

__device__ __forceinline__ float dpp_shr1(float x) {  // lane L gets lane L-1 (16-lane rows)
  return __int_as_float(__builtin_amdgcn_update_dpp(0, __float_as_int(x), 0x111, 0xf, 0xf, false));
}
__device__ __forceinline__ float dpp_shl1(float x) {  // lane L gets lane L+1
  return __int_as_float(__builtin_amdgcn_update_dpp(0, __float_as_int(x), 0x101, 0xf, 0xf, false));
}

// ---------------------------------------------------------------------------
// prep: Wt[c][o=384] = {wq|wk|wv}[o][c];  pwt[g][kd][d=9][o=32][i=32] bf16
// ---------------------------------------------------------------------------
__global__ __launch_bounds__(256) void prep_kernel(
    const float* __restrict__ wq, const float* __restrict__ wk, const float* __restrict__ wv,
    const float* __restrict__ pw, float* __restrict__ Wt, __bf16* __restrict__ pwt) {
  int idx = blockIdx.x * 256 + threadIdx.x;
  const int NPW = 4 * 16 * 9 * 32 * 32;  // 589824
  if (idx < NPW) {
    int i  = idx & 31;
    int ol = (idx >> 5) & 31;
    int d  = (idx >> 10) % 9;
    int r  = (idx >> 10) / 9;   // g*16+kd
    int kd = r & 15;
    int g  = r >> 4;
    int o  = g * 32 + ol;
    pwt[idx] = (__bf16)pw[((o * 32 + i) * 16 + kd) * 9 + d];
  } else {
    int widx = idx - NPW;
    if (widx < 128 * 384) {
      int o = widx % 384;
      int c = widx / 384;
      const float* __restrict__ src = (o < 128) ? wq : (o < 256 ? wk : wv);
      Wt[widx] = src[(o & 127) * 128 + c];
    }
  }
}

// ---------------------------------------------------------------------------
// LN stats: per-pixel mean / rsqrt(var+eps).  grid (144,4) x 64 threads.
// ---------------------------------------------------------------------------
__global__ __launch_bounds__(64) void ln_stats_kernel(
    const float* __restrict__ vid, float* __restrict__ mu, float* __restrict__ rs) {
  int pix = blockIdx.x * 64 + threadIdx.x;
  int f = blockIdx.y;
  const float* __restrict__ vp = vid + (size_t)f * 128 * 9216 + pix;
  float s = 0.f, s2 = 0.f;
  #pragma unroll 8
  for (int c = 0; c < 128; ++c) { float x = vp[(size_t)c * 9216]; s += x; s2 += x * x; }
  float m_ = s * (1.f / 128.f);
  float v_ = fmaxf(s2 * (1.f / 128.f) - m_ * m_, 0.f);
  mu[f * 9216 + pix] = m_;
  rs[f * 9216 + pix] = rsqrtf(v_ + 1e-6f);
}

// ---------------------------------------------------------------------------
// QKV GEMM: 128x128 tile, K=128 in 4x32 chunks, 512 threads (8 waves),
// register double-buffered staging.  grid (3, 288); blockIdx.x selects q/k/v.
// q,k: fp32 [t*4+head][pix][c32].  v: bf16 same layout.
// ---------------------------------------------------------------------------
__global__ __launch_bounds__(512) void qkv_gemm_kernel(
    const float* __restrict__ vid, const float* __restrict__ mu, const float* __restrict__ rs,
    const float* __restrict__ lnw, const float* __restrict__ lnb,
    const float* __restrict__ Wt, const float* __restrict__ bq, const float* __restrict__ bk,
    const float* __restrict__ bv, float* __restrict__ qb, float* __restrict__ kb,
    __bf16* __restrict__ vbbf) {
  __shared__ __align__(16) float Xs[32][128];
  __shared__ __align__(16) float Ws[32][128];
  __shared__ float muL[128], rsL[128], lwS[128], lbS[128];
  int tid = threadIdx.x;
  int mt = blockIdx.y;
  int N0 = blockIdx.x * 128;
  int f  = mt / 72;
  int pf = (mt % 72) * 128;

  if (tid < 128) {
    muL[tid] = mu[f * 9216 + pf + tid];
    rsL[tid] = rs[f * 9216 + pf + tid];
  } else if (tid < 256) {
    int t2 = tid - 128;
    lwS[t2] = lnw[t2];
    lbS[t2] = lnb[t2];
  }

  int tx = tid & 15, ty = tid >> 4;   // ty 0..31
  int m0 = ty * 4;
  int sm = tid & 127;                  // staging column
  int sk = tid >> 7;                   // staging row base (0..3)
  float acc[4][8];
  #pragma unroll
  for (int a = 0; a < 4; ++a)
    #pragma unroll
    for (int b = 0; b < 8; ++b) acc[a][b] = 0.f;

  const size_t vbase = (size_t)f * 128 * 9216 + pf;
  float xr[8], wr[8];

  #pragma unroll
  for (int it = 0; it < 8; ++it) {
    int kk = sk + 4 * it;
    xr[it] = vid[vbase + (size_t)kk * 9216 + sm];
    wr[it] = Wt[(size_t)kk * 384 + N0 + sm];
  }
  __syncthreads();
  #pragma unroll
  for (int it = 0; it < 8; ++it) {
    int kk = sk + 4 * it;
    Xs[kk][sm] = (xr[it] - muL[sm]) * rsL[sm] * lwS[kk] + lbS[kk];
    Ws[kk][sm] = wr[it];
  }
  __syncthreads();

  for (int kc = 0; kc < 4; ++kc) {
    if (kc < 3) {
      #pragma unroll
      for (int it = 0; it < 8; ++it) {
        int kk = sk + 4 * it;
        int c = (kc + 1) * 32 + kk;
        xr[it] = vid[vbase + (size_t)c * 9216 + sm];
        wr[it] = Wt[(size_t)c * 384 + N0 + sm];
      }
    }
    #pragma unroll 4
    for (int kk = 0; kk < 32; ++kk) {
      float xa[4], wa[8];
      *(float4*)&xa[0] = *(const float4*)&Xs[kk][m0];
      *(float4*)&wa[0] = *(const float4*)&Ws[kk][tx * 4];
      *(float4*)&wa[4] = *(const float4*)&Ws[kk][64 + tx * 4];
      #pragma unroll
      for (int a = 0; a < 4; ++a)
        #pragma unroll
        for (int b = 0; b < 8; ++b)
          acc[a][b] = fmaf(xa[a], wa[b], acc[a][b]);
    }
    if (kc < 3) {
      __syncthreads();
      #pragma unroll
      for (int it = 0; it < 8; ++it) {
        int kk = sk + 4 * it;
        int c = (kc + 1) * 32 + kk;
        Xs[kk][sm] = (xr[it] - muL[sm]) * rsL[sm] * lwS[c] + lbS[c];
        Ws[kk][sm] = wr[it];
      }
      __syncthreads();
    }
  }

  int sel = blockIdx.x;
  int nlo = tx * 4, nhi = 64 + tx * 4;
  int hlo = nlo >> 5, clo = nlo & 31;
  int hhi = nhi >> 5, chi = nhi & 31;
  const float* __restrict__ bias = (sel == 0) ? bq : (sel == 1 ? bk : bv);
  float4 blo = make_float4(bias[nlo], bias[nlo + 1], bias[nlo + 2], bias[nlo + 3]);
  float4 bhi = make_float4(bias[nhi], bias[nhi + 1], bias[nhi + 2], bias[nhi + 3]);
  size_t base_lo = (size_t)(f * 4 + hlo) * 9216 * 32 + clo;
  size_t base_hi = (size_t)(f * 4 + hhi) * 9216 * 32 + chi;
  if (sel < 2) {
    float* __restrict__ dst = (sel == 0) ? qb : kb;
    #pragma unroll
    for (int a = 0; a < 4; ++a) {
      size_t poff = (size_t)(pf + m0 + a) * 32;
      *(float4*)&dst[base_lo + poff] = make_float4(acc[a][0] + blo.x, acc[a][1] + blo.y,
                                                   acc[a][2] + blo.z, acc[a][3] + blo.w);
      *(float4*)&dst[base_hi + poff] = make_float4(acc[a][4] + bhi.x, acc[a][5] + bhi.y,
                                                   acc[a][6] + bhi.z, acc[a][7] + bhi.w);
    }
  } else {
    #pragma unroll
    for (int a = 0; a < 4; ++a) {
      size_t poff = (size_t)(pf + m0 + a) * 32;
      bf16x4 lo4, hi4;
      lo4[0] = (__bf16)(acc[a][0] + blo.x); lo4[1] = (__bf16)(acc[a][1] + blo.y);
      lo4[2] = (__bf16)(acc[a][2] + blo.z); lo4[3] = (__bf16)(acc[a][3] + blo.w);
      hi4[0] = (__bf16)(acc[a][4] + bhi.x); hi4[1] = (__bf16)(acc[a][5] + bhi.y);
      hi4[2] = (__bf16)(acc[a][6] + bhi.z); hi4[3] = (__bf16)(acc[a][7] + bhi.w);
      *(bf16x4*)&vbbf[base_lo + poff] = lo4;
      *(bf16x4*)&vbbf[base_hi + poff] = hi4;
    }
  }
}

// ---------------------------------------------------------------------------
// search + topk + softmax.  16x16 s-region tile (inner 14x14 queries).
// grid (49, 16), 256 threads, 3 blocks/CU (47 KB LDS).
// ---------------------------------------------------------------------------
__global__ __launch_bounds__(256, 3) void search_kernel(
    const float* __restrict__ qb, const float* __restrict__ kb,
    float* __restrict__ wgtb, int* __restrict__ indb) {
  __shared__ __align__(16) float klds[16 * 22 * 32];   // 45056 B
  __shared__ float slds[2][256];
  int tid = threadIdx.x;
  int th = blockIdx.y;
  int tile = blockIdx.x;
  int iy0 = (tile / 7) * 14, ix0 = (tile % 7) * 14;
  const float* __restrict__ kbase = kb + (size_t)th * 9216 * 32;

  #pragma unroll
  for (int it = 0; it < 11; ++it) {
    int i = it * 256 + tid;
    int r = i / 176, rem = i % 176;
    int col = rem >> 3, c4 = rem & 7;
    int gy = iy0 - 4 + r, gx = ix0 - 4 + col;
    float4 val = make_float4(0.f, 0.f, 0.f, 0.f);
    if ((unsigned)gy < 96u && (unsigned)gx < 96u)
      val = *(const float4*)&kbase[(size_t)(gy * 96 + gx) * 32 + c4 * 4];
    int p = r * 22 + col;
    *(float4*)&klds[p * 32 + ((c4 ^ (p & 7)) << 2)] = val;
  }

  int sy = tid >> 4, sx = tid & 15;
  int qy = iy0 - 1 + sy, qx = ix0 - 1 + sx;
  bool qok = (unsigned)qy < 96u && (unsigned)qx < 96u;
  float4 qv[8];
  #pragma unroll
  for (int j = 0; j < 8; ++j) qv[j] = make_float4(0.f, 0.f, 0.f, 0.f);
  if (qok) {
    const float* __restrict__ qp = qb + ((size_t)th * 9216 + qy * 96 + qx) * 32;
    #pragma unroll
    for (int j = 0; j < 8; ++j) qv[j] = *(const float4*)&qp[j * 4];
  }
  bool inner = (sy >= 1) && (sy <= 14) && (sx >= 1) && (sx <= 14) && qok;

  float tv[16]; int tix[16];
  #pragma unroll
  for (int j = 0; j < 16; ++j) { tv[j] = -3.0e38f; tix[j] = 0; }
  __syncthreads();

  #pragma unroll 1
  for (int dy = 0; dy < 7; ++dy) {
    if (dy > 0) {
      if (tid < 176) {
        int col = tid >> 3, c4 = tid & 7;
        int r = dy + 15;
        int gy = iy0 - 4 + r, gx = ix0 - 4 + col;
        float4 val = make_float4(0.f, 0.f, 0.f, 0.f);
        if ((unsigned)gy < 96u && (unsigned)gx < 96u)
          val = *(const float4*)&kbase[(size_t)(gy * 96 + gx) * 32 + c4 * 4];
        int p = (r & 15) * 22 + col;
        *(float4*)&klds[p * 32 + ((c4 ^ (p & 7)) << 2)] = val;
      }
      __syncthreads();
    }
    #pragma unroll 1
    for (int dx = 0; dx < 7; ++dx) {
      int oi = dy * 7 + dx;
      int p = ((sy + dy) & 15) * 22 + (sx + dx);
      const float* __restrict__ kp = &klds[p * 32];
      int sw = p & 7;
      float sdot = 0.f;
      #pragma unroll
      for (int j = 0; j < 8; ++j) {
        float4 kq = *(const float4*)&kp[(j ^ sw) << 2];
        sdot += qv[j].x * kq.x + qv[j].y * kq.y + qv[j].z * kq.z + qv[j].w * kq.w;
      }
      float h = sdot + dpp_shr1(sdot) + dpp_shl1(sdot);
      slds[oi & 1][tid] = h;
      __syncthreads();
      if (inner) {
        const float* __restrict__ sb = slds[oi & 1];
        float sc = h + sb[tid - 16] + sb[tid + 16];
        float cv = sc; int ci = oi;
        #pragma unroll
        for (int j = 0; j < 16; ++j) {
          bool gt = cv > tv[j];
          float mx = fmaxf(tv[j], cv);
          float mn = fminf(tv[j], cv);
          int nt = gt ? ci : tix[j];
          ci = gt ? tix[j] : ci;
          tv[j] = mx; cv = mn; tix[j] = nt;
        }
      }
    }
  }

  if (inner) {
    float mx = tv[0];
    float e[16], ssum = 0.f;
    #pragma unroll
    for (int j = 0; j < 16; ++j) { e[j] = __expf(tv[j] - mx); ssum += e[j]; }
    float inv = 1.f / ssum;
    size_t base = ((size_t)th * 9216 + qy * 96 + qx) * 16;
    #pragma unroll
    for (int j = 0; j < 4; ++j) {
      *(float4*)&wgtb[base + j * 4] =
          make_float4(e[j*4] * inv, e[j*4+1] * inv, e[j*4+2] * inv, e[j*4+3] * inv);
      *(int4*)&indb[base + j * 4] = make_int4(tix[j*4], tix[j*4+1], tix[j*4+2], tix[j*4+3]);
    }
  }
}

// ---------------------------------------------------------------------------
// fused gather + implicit-conv GEMM, XCD-swizzled, T14 reg-prefetch.
// grid 576 (1D), 512 threads (8 waves x 2 rows).  16x16 px tile, 18x18 halo.
// Stride 40 bf16 (16B-aligned rows — stride 36 measured -17 us, ERR round 9).
// dx-major MFMA with 4-frag A register cache: 12 A + 18 B LDS reads per
// wave-kd feed 36 MFMAs (vs 18+18 dy-major).
// ---------------------------------------------------------------------------
__global__ __launch_bounds__(512) void proj_kernel(
    const __bf16* __restrict__ vb, const float* __restrict__ wgtb, const int* __restrict__ indb,
    const __bf16* __restrict__ pwt, const float* __restrict__ pb, float* __restrict__ outp) {
  __shared__ __align__(16) __bf16 Alds[324 * 40];
  __shared__ __align__(16) __bf16 Blds[288 * 40];
  int tid = threadIdx.x;
  int bid = blockIdx.x;
  int wg = (bid & 7) * 72 + (bid >> 3);   // XCD-contiguous remap (576 = 8*72)
  int th = wg / 36;                        // f*4+g
  int tile = wg % 36;
  int g = th & 3;
  int ty0 = (tile / 6) * 16, tx0 = (tile % 6) * 16;
  int lane = tid & 63, wid = tid >> 6;     // wid 0..7
  int kg = lane >> 4, lr = lane & 15;

  bool gact = tid < 324;
  int ry = tid / 18, rx = tid % 18;
  int gy = ty0 - 1 + ry, gx = tx0 - 1 + rx;
  bool inb = gact && (unsigned)gy < 96u && (unsigned)gx < 96u;
  const __bf16* __restrict__ vbase = vb + (size_t)th * 9216 * 32;
  size_t pxoff = inb ? (size_t)(gy * 96 + gx) : 0;
  const int*   __restrict__ ibase = indb + ((size_t)th * 9216 + pxoff) * 16;
  const float* __restrict__ wbase = wgtb + ((size_t)th * 9216 + pxoff) * 16;

  f32x4 acc[2][2];
  acc[0][0] = (f32x4)(0.0f); acc[0][1] = (f32x4)(0.0f);
  acc[1][0] = (f32x4)(0.0f); acc[1][1] = (f32x4)(0.0f);

  int4 iw_i = make_int4(0, 0, 0, 0);
  float4 iw_w = make_float4(0.f, 0.f, 0.f, 0.f);
  int4 vr[4];
  vr[0] = vr[1] = vr[2] = vr[3] = make_int4(0, 0, 0, 0);
  float wcur = 0.f;

  if (inb) {
    iw_i = *(const int4*)&ibase[0];
    iw_w = *(const float4*)&wbase[0];
    int ind0 = iw_i.x;
    int ny = gy + ind0 / 7 - 3, nx = gx + ind0 % 7 - 3;
    if ((unsigned)ny < 96u && (unsigned)nx < 96u) {
      const int4* __restrict__ vp = (const int4*)(vbase + (size_t)(ny * 96 + nx) * 32);
      vr[0] = vp[0]; vr[1] = vp[1]; vr[2] = vp[2]; vr[3] = vp[3];
    }
    wcur = iw_w.x;
  }

  for (int kdb = 0; kdb < 4; ++kdb) {
    #pragma unroll
    for (int kb = 0; kb < 4; ++kb) {
      int kd = kdb * 4 + kb;
      __syncthreads();
      if (gact) {
        __bf16 tmp[32];
        #pragma unroll
        for (int wv = 0; wv < 4; ++wv) {
          unsigned uu[4] = {(unsigned)vr[wv].x, (unsigned)vr[wv].y,
                            (unsigned)vr[wv].z, (unsigned)vr[wv].w};
          #pragma unroll
          for (int j2 = 0; j2 < 4; ++j2) {
            float lo = __uint_as_float(uu[j2] << 16);
            float hi = __uint_as_float(uu[j2] & 0xffff0000u);
            tmp[wv * 8 + j2 * 2]     = (__bf16)(lo * wcur);
            tmp[wv * 8 + j2 * 2 + 1] = (__bf16)(hi * wcur);
          }
        }
        __bf16* dst = &Alds[tid * 40];
        *(int4*)&dst[0]  = *(const int4*)&tmp[0];
        *(int4*)&dst[8]  = *(const int4*)&tmp[8];
        *(int4*)&dst[16] = *(const int4*)&tmp[16];
        *(int4*)&dst[24] = *(const int4*)&tmp[24];
      }
      {
        const __bf16* __restrict__ bsrc = pwt + (size_t)(g * 16 + kd) * 9216;
        #pragma unroll
        for (int itb = 0; itb < 3; ++itb) {
          int i = itb * 512 + tid;
          if (i < 1152) {
            int row = i >> 2, c = i & 3;
            *(int4*)&Blds[row * 40 + c * 8] = *(const int4*)&bsrc[row * 32 + c * 8];
          }
        }
      }
      __syncthreads();
      if (kd < 15) {
        int indn; float wn;
        if (kb == 3) {
          if (inb) {
            iw_i = *(const int4*)&ibase[kd + 1];
            iw_w = *(const float4*)&wbase[kd + 1];
          }
          indn = iw_i.x; wn = iw_w.x;
        } else {
          indn = (kb == 0) ? iw_i.y : (kb == 1) ? iw_i.z : iw_i.w;
          wn   = (kb == 0) ? iw_w.y : (kb == 1) ? iw_w.z : iw_w.w;
        }
        vr[0] = vr[1] = vr[2] = vr[3] = make_int4(0, 0, 0, 0);
        if (inb) {
          int ny = gy + indn / 7 - 3, nx = gx + indn % 7 - 3;
          if ((unsigned)ny < 96u && (unsigned)nx < 96u) {
            const int4* __restrict__ vp = (const int4*)(vbase + (size_t)(ny * 96 + nx) * 32);
            vr[0] = vp[0]; vr[1] = vp[1]; vr[2] = vp[2]; vr[3] = vp[3];
          }
        }
        wcur = wn;
      }
      // dx-major MFMA: A frags for rows wid*2..wid*2+3 at col lr+dx2, read once
      #pragma unroll
      for (int dx2 = 0; dx2 < 3; ++dx2) {
        bf16x8 a[4];
        #pragma unroll
        for (int r = 0; r < 4; ++r)
          a[r] = *(const bf16x8*)&Alds[((wid * 2 + r) * 18 + lr + dx2) * 40 + kg * 8];
        #pragma unroll
        for (int dy2 = 0; dy2 < 3; ++dy2) {
          int d = dy2 * 3 + dx2;
          bf16x8 b0 = *(const bf16x8*)&Blds[(d * 32 + lr) * 40 + kg * 8];
          bf16x8 b1 = *(const bf16x8*)&Blds[(d * 32 + 16 + lr) * 40 + kg * 8];
          acc[0][0] = __builtin_amdgcn_mfma_f32_16x16x32_bf16(a[dy2],     b0, acc[0][0], 0, 0, 0);
          acc[0][1] = __builtin_amdgcn_mfma_f32_16x16x32_bf16(a[dy2],     b1, acc[0][1], 0, 0, 0);
          acc[1][0] = __builtin_amdgcn_mfma_f32_16x16x32_bf16(a[dy2 + 1], b0, acc[1][0], 0, 0, 0);
          acc[1][1] = __builtin_amdgcn_mfma_f32_16x16x32_bf16(a[dy2 + 1], b1, acc[1][1], 0, 0, 0);
        }
      }
    }
  }

  int x0 = tx0 + kg * 4;
  int f = th >> 2;
  #pragma unroll
  for (int mt = 0; mt < 2; ++mt) {
    int y = ty0 + wid * 2 + mt;
    #pragma unroll
    for (int nt = 0; nt < 2; ++nt) {
      int o = g * 32 + nt * 16 + lr;
      float bias = pb[o];
      float4 res = make_float4(acc[mt][nt][0] + bias, acc[mt][nt][1] + bias,
                               acc[mt][nt][2] + bias, acc[mt][nt][3] + bias);
      *(float4*)&outp[(size_t)(f * 128 + o) * 9216 + y * 96 + x0] = res;
    }
  }
}

// ---------------------------------------------------------------------------
extern "C" void kernel_launch(void* const* d_in, const int* in_sizes, int n_in,
                              void* d_out, int out_size, void* d_ws, size_t ws_size,
                              hipStream_t stream) {
  const float* vid = (const float*)d_in[0];
  const float* lnw = (const float*)d_in[1];
  const float* lnb = (const float*)d_in[2];
  const float* wq  = (const float*)d_in[3];
  const float* bq  = (const float*)d_in[4];
  const float* wk  = (const float*)d_in[5];
  const float* bk  = (const float*)d_in[6];
  const float* wv_ = (const float*)d_in[7];
  const float* bv  = (const float*)d_in[8];
  const float* pw  = (const float*)d_in[9];
  const float* pb  = (const float*)d_in[10];
  float* outp = (float*)d_out;

  const size_t SZ_T  = (size_t)16 * 9216 * 32 * 4;     // q/k fp32 each
  const size_t SZ_TB = (size_t)16 * 9216 * 32 * 2;     // v bf16
  const size_t SZ_W  = (size_t)16 * 9216 * 16 * 4;     // wgt / ind
  const size_t SZ_WT = 128 * 384 * 4;
  const size_t SZ_PW = (size_t)4 * 16 * 9 * 32 * 32 * 2;
  const size_t SZ_MU = (size_t)4 * 9216 * 4;

  char* p = (char*)d_ws;
  float* qb = (float*)p;        p += SZ_T;
  float* kb = (float*)p;        p += SZ_T;
  __bf16* vbbf = (__bf16*)p;    p += SZ_TB;
  float* wgtb = (float*)p;      p += SZ_W;
  int*   indb = (int*)p;        p += SZ_W;
  float* Wt = (float*)p;        p += SZ_WT;
  __bf16* pwt = (__bf16*)p;     p += SZ_PW;
  float* mu = (float*)p;        p += SZ_MU;
  float* rs = (float*)p;

  prep_kernel<<<2496, 256, 0, stream>>>(wq, wk, wv_, pw, Wt, pwt);
  ln_stats_kernel<<<dim3(144, 4), 64, 0, stream>>>(vid, mu, rs);
  qkv_gemm_kernel<<<dim3(3, 288), 512, 0, stream>>>(vid, mu, rs, lnw, lnb, Wt, bq, bk, bv,
                                                    qb, kb, vbbf);
  search_kernel<<<dim3(49, 16), 256, 0, stream>>>(qb, kb, wgtb, indb);
  proj_kernel<<<576, 512, 0, stream>>>(vbbf, wgtb, indb, pwt, pb, outp);
}

// Round 11
// 226.320 us; speedup vs baseline: 1.1567x; 1.0138x over previous
//
#include <hip/hip_runtime.h>

// NonLocalAttentionStack on MI355X.
// Dims: B=1, T=4, C=128, H=W=96, NHEADS=4 (c=32/head), WS=7 (49 cands), PS=3, K=16.
// Pipeline: prep -> ln_stats -> QKV (fp32 GEMM; v output bf16) ->
//           search+topk+softmax (fp32, 16x16 tile, rolling k-band, DPP box-sum) ->
//           fused gather+implicit-conv MFMA GEMM (XCD-swizzled, 2-deep gather
//           prefetch, A+B LDS double-buffer -> ONE barrier per kd, stride-32
//           chunk-XOR-swizzled LDS rows: 16B-aligned b128 at bank floor).

typedef float  f32x4  __attribute__((ext_vector_type(4)));
typedef __bf16 bf16x8 __attribute__((ext_vector_type(8)));
typedef __bf16 bf16x4 __attribute__((ext_vector_type(4)));

__device__ __forceinline__ float dpp_shr1(float x) {  // lane L gets lane L-1 (16-lane rows)
  return __int_as_float(__builtin_amdgcn_update_dpp(0, __float_as_int(x), 0x111, 0xf, 0xf, false));
}
__device__ __forceinline__ float dpp_shl1(float x) {  // lane L gets lane L+1
  return __int_as_float(__builtin_amdgcn_update_dpp(0, __float_as_int(x), 0x101, 0xf, 0xf, false));
}

// ---------------------------------------------------------------------------
// prep: Wt[c][o=384] = {wq|wk|wv}[o][c];  pwt[g][kd][d=9][o=32][i=32] bf16
// ---------------------------------------------------------------------------
__global__ __launch_bounds__(256) void prep_kernel(
    const float* __restrict__ wq, const float* __restrict__ wk, const float* __restrict__ wv,
    const float* __restrict__ pw, float* __restrict__ Wt, __bf16* __restrict__ pwt) {
  int idx = blockIdx.x * 256 + threadIdx.x;
  const int NPW = 4 * 16 * 9 * 32 * 32;  // 589824
  if (idx < NPW) {
    int i  = idx & 31;
    int ol = (idx >> 5) & 31;
    int d  = (idx >> 10) % 9;
    int r  = (idx >> 10) / 9;   // g*16+kd
    int kd = r & 15;
    int g  = r >> 4;
    int o  = g * 32 + ol;
    pwt[idx] = (__bf16)pw[((o * 32 + i) * 16 + kd) * 9 + d];
  } else {
    int widx = idx - NPW;
    if (widx < 128 * 384) {
      int o = widx % 384;
      int c = widx / 384;
      const float* __restrict__ src = (o < 128) ? wq : (o < 256 ? wk : wv);
      Wt[widx] = src[(o & 127) * 128 + c];
    }
  }
}

// ---------------------------------------------------------------------------
// LN stats: per-pixel mean / rsqrt(var+eps).  grid (144,4) x 64 threads.
// ---------------------------------------------------------------------------
__global__ __launch_bounds__(64) void ln_stats_kernel(
    const float* __restrict__ vid, float* __restrict__ mu, float* __restrict__ rs) {
  int pix = blockIdx.x * 64 + threadIdx.x;
  int f = blockIdx.y;
  const float* __restrict__ vp = vid + (size_t)f * 128 * 9216 + pix;
  float s = 0.f, s2 = 0.f;
  #pragma unroll 8
  for (int c = 0; c < 128; ++c) { float x = vp[(size_t)c * 9216]; s += x; s2 += x * x; }
  float m_ = s * (1.f / 128.f);
  float v_ = fmaxf(s2 * (1.f / 128.f) - m_ * m_, 0.f);
  mu[f * 9216 + pix] = m_;
  rs[f * 9216 + pix] = rsqrtf(v_ + 1e-6f);
}

// ---------------------------------------------------------------------------
// QKV GEMM: 128x128 tile, K=128 in 4x32 chunks, 512 threads (8 waves),
// register double-buffered staging.  grid (3, 288); blockIdx.x selects q/k/v.
// q,k: fp32 [t*4+head][pix][c32].  v: bf16 same layout.
// ---------------------------------------------------------------------------
__global__ __launch_bounds__(512) void qkv_gemm_kernel(
    const float* __restrict__ vid, const float* __restrict__ mu, const float* __restrict__ rs,
    const float* __restrict__ lnw, const float* __restrict__ lnb,
    const float* __restrict__ Wt, const float* __restrict__ bq, const float* __restrict__ bk,
    const float* __restrict__ bv, float* __restrict__ qb, float* __restrict__ kb,
    __bf16* __restrict__ vbbf) {
  __shared__ __align__(16) float Xs[32][128];
  __shared__ __align__(16) float Ws[32][128];
  __shared__ float muL[128], rsL[128], lwS[128], lbS[128];
  int tid = threadIdx.x;
  int mt = blockIdx.y;
  int N0 = blockIdx.x * 128;
  int f  = mt / 72;
  int pf = (mt % 72) * 128;

  if (tid < 128) {
    muL[tid] = mu[f * 9216 + pf + tid];
    rsL[tid] = rs[f * 9216 + pf + tid];
  } else if (tid < 256) {
    int t2 = tid - 128;
    lwS[t2] = lnw[t2];
    lbS[t2] = lnb[t2];
  }

  int tx = tid & 15, ty = tid >> 4;   // ty 0..31
  int m0 = ty * 4;
  int sm = tid & 127;                  // staging column
  int sk = tid >> 7;                   // staging row base (0..3)
  float acc[4][8];
  #pragma unroll
  for (int a = 0; a < 4; ++a)
    #pragma unroll
    for (int b = 0; b < 8; ++b) acc[a][b] = 0.f;

  const size_t vbase = (size_t)f * 128 * 9216 + pf;
  float xr[8], wr[8];

  #pragma unroll
  for (int it = 0; it < 8; ++it) {
    int kk = sk + 4 * it;
    xr[it] = vid[vbase + (size_t)kk * 9216 + sm];
    wr[it] = Wt[(size_t)kk * 384 + N0 + sm];
  }
  __syncthreads();
  #pragma unroll
  for (int it = 0; it < 8; ++it) {
    int kk = sk + 4 * it;
    Xs[kk][sm] = (xr[it] - muL[sm]) * rsL[sm] * lwS[kk] + lbS[kk];
    Ws[kk][sm] = wr[it];
  }
  __syncthreads();

  for (int kc = 0; kc < 4; ++kc) {
    if (kc < 3) {
      #pragma unroll
      for (int it = 0; it < 8; ++it) {
        int kk = sk + 4 * it;
        int c = (kc + 1) * 32 + kk;
        xr[it] = vid[vbase + (size_t)c * 9216 + sm];
        wr[it] = Wt[(size_t)c * 384 + N0 + sm];
      }
    }
    #pragma unroll 4
    for (int kk = 0; kk < 32; ++kk) {
      float xa[4], wa[8];
      *(float4*)&xa[0] = *(const float4*)&Xs[kk][m0];
      *(float4*)&wa[0] = *(const float4*)&Ws[kk][tx * 4];
      *(float4*)&wa[4] = *(const float4*)&Ws[kk][64 + tx * 4];
      #pragma unroll
      for (int a = 0; a < 4; ++a)
        #pragma unroll
        for (int b = 0; b < 8; ++b)
          acc[a][b] = fmaf(xa[a], wa[b], acc[a][b]);
    }
    if (kc < 3) {
      __syncthreads();
      #pragma unroll
      for (int it = 0; it < 8; ++it) {
        int kk = sk + 4 * it;
        int c = (kc + 1) * 32 + kk;
        Xs[kk][sm] = (xr[it] - muL[sm]) * rsL[sm] * lwS[c] + lbS[c];
        Ws[kk][sm] = wr[it];
      }
      __syncthreads();
    }
  }

  int sel = blockIdx.x;
  int nlo = tx * 4, nhi = 64 + tx * 4;
  int hlo = nlo >> 5, clo = nlo & 31;
  int hhi = nhi >> 5, chi = nhi & 31;
  const float* __restrict__ bias = (sel == 0) ? bq : (sel == 1 ? bk : bv);
  float4 blo = make_float4(bias[nlo], bias[nlo + 1], bias[nlo + 2], bias[nlo + 3]);
  float4 bhi = make_float4(bias[nhi], bias[nhi + 1], bias[nhi + 2], bias[nhi + 3]);
  size_t base_lo = (size_t)(f * 4 + hlo) * 9216 * 32 + clo;
  size_t base_hi = (size_t)(f * 4 + hhi) * 9216 * 32 + chi;
  if (sel < 2) {
    float* __restrict__ dst = (sel == 0) ? qb : kb;
    #pragma unroll
    for (int a = 0; a < 4; ++a) {
      size_t poff = (size_t)(pf + m0 + a) * 32;
      *(float4*)&dst[base_lo + poff] = make_float4(acc[a][0] + blo.x, acc[a][1] + blo.y,
                                                   acc[a][2] + blo.z, acc[a][3] + blo.w);
      *(float4*)&dst[base_hi + poff] = make_float4(acc[a][4] + bhi.x, acc[a][5] + bhi.y,
                                                   acc[a][6] + bhi.z, acc[a][7] + bhi.w);
    }
  } else {
    #pragma unroll
    for (int a = 0; a < 4; ++a) {
      size_t poff = (size_t)(pf + m0 + a) * 32;
      bf16x4 lo4, hi4;
      lo4[0] = (__bf16)(acc[a][0] + blo.x); lo4[1] = (__bf16)(acc[a][1] + blo.y);
      lo4[2] = (__bf16)(acc[a][2] + blo.z); lo4[3] = (__bf16)(acc[a][3] + blo.w);
      hi4[0] = (__bf16)(acc[a][4] + bhi.x); hi4[1] = (__bf16)(acc[a][5] + bhi.y);
      hi4[2] = (__bf16)(acc[a][6] + bhi.z); hi4[3] = (__bf16)(acc[a][7] + bhi.w);
      *(bf16x4*)&vbbf[base_lo + poff] = lo4;
      *(bf16x4*)&vbbf[base_hi + poff] = hi4;
    }
  }
}

// ---------------------------------------------------------------------------
// search + topk + softmax.  16x16 s-region tile (inner 14x14 queries).
// grid (49, 16), 256 threads, 3 blocks/CU (47 KB LDS).
// ---------------------------------------------------------------------------
__global__ __launch_bounds__(256, 3) void search_kernel(
    const float* __restrict__ qb, const float* __restrict__ kb,
    float* __restrict__ wgtb, int* __restrict__ indb) {
  __shared__ __align__(16) float klds[16 * 22 * 32];   // 45056 B
  __shared__ float slds[2][256];
  int tid = threadIdx.x;
  int th = blockIdx.y;
  int tile = blockIdx.x;
  int iy0 = (tile / 7) * 14, ix0 = (tile % 7) * 14;
  const float* __restrict__ kbase = kb + (size_t)th * 9216 * 32;

  #pragma unroll
  for (int it = 0; it < 11; ++it) {
    int i = it * 256 + tid;
    int r = i / 176, rem = i % 176;
    int col = rem >> 3, c4 = rem & 7;
    int gy = iy0 - 4 + r, gx = ix0 - 4 + col;
    float4 val = make_float4(0.f, 0.f, 0.f, 0.f);
    if ((unsigned)gy < 96u && (unsigned)gx < 96u)
      val = *(const float4*)&kbase[(size_t)(gy * 96 + gx) * 32 + c4 * 4];
    int p = r * 22 + col;
    *(float4*)&klds[p * 32 + ((c4 ^ (p & 7)) << 2)] = val;
  }

  int sy = tid >> 4, sx = tid & 15;
  int qy = iy0 - 1 + sy, qx = ix0 - 1 + sx;
  bool qok = (unsigned)qy < 96u && (unsigned)qx < 96u;
  float4 qv[8];
  #pragma unroll
  for (int j = 0; j < 8; ++j) qv[j] = make_float4(0.f, 0.f, 0.f, 0.f);
  if (qok) {
    const float* __restrict__ qp = qb + ((size_t)th * 9216 + qy * 96 + qx) * 32;
    #pragma unroll
    for (int j = 0; j < 8; ++j) qv[j] = *(const float4*)&qp[j * 4];
  }
  bool inner = (sy >= 1) && (sy <= 14) && (sx >= 1) && (sx <= 14) && qok;

  float tv[16]; int tix[16];
  #pragma unroll
  for (int j = 0; j < 16; ++j) { tv[j] = -3.0e38f; tix[j] = 0; }
  __syncthreads();

  #pragma unroll 1
  for (int dy = 0; dy < 7; ++dy) {
    if (dy > 0) {
      if (tid < 176) {
        int col = tid >> 3, c4 = tid & 7;
        int r = dy + 15;
        int gy = iy0 - 4 + r, gx = ix0 - 4 + col;
        float4 val = make_float4(0.f, 0.f, 0.f, 0.f);
        if ((unsigned)gy < 96u && (unsigned)gx < 96u)
          val = *(const float4*)&kbase[(size_t)(gy * 96 + gx) * 32 + c4 * 4];
        int p = (r & 15) * 22 + col;
        *(float4*)&klds[p * 32 + ((c4 ^ (p & 7)) << 2)] = val;
      }
      __syncthreads();
    }
    #pragma unroll 1
    for (int dx = 0; dx < 7; ++dx) {
      int oi = dy * 7 + dx;
      int p = ((sy + dy) & 15) * 22 + (sx + dx);
      const float* __restrict__ kp = &klds[p * 32];
      int sw = p & 7;
      float sdot = 0.f;
      #pragma unroll
      for (int j = 0; j < 8; ++j) {
        float4 kq = *(const float4*)&kp[(j ^ sw) << 2];
        sdot += qv[j].x * kq.x + qv[j].y * kq.y + qv[j].z * kq.z + qv[j].w * kq.w;
      }
      float h = sdot + dpp_shr1(sdot) + dpp_shl1(sdot);
      slds[oi & 1][tid] = h;
      __syncthreads();
      if (inner) {
        const float* __restrict__ sb = slds[oi & 1];
        float sc = h + sb[tid - 16] + sb[tid + 16];
        float cv = sc; int ci = oi;
        #pragma unroll
        for (int j = 0; j < 16; ++j) {
          bool gt = cv > tv[j];
          float mx = fmaxf(tv[j], cv);
          float mn = fminf(tv[j], cv);
          int nt = gt ? ci : tix[j];
          ci = gt ? tix[j] : ci;
          tv[j] = mx; cv = mn; tix[j] = nt;
        }
      }
    }
  }

  if (inner) {
    float mx = tv[0];
    float e[16], ssum = 0.f;
    #pragma unroll
    for (int j = 0; j < 16; ++j) { e[j] = __expf(tv[j] - mx); ssum += e[j]; }
    float inv = 1.f / ssum;
    size_t base = ((size_t)th * 9216 + qy * 96 + qx) * 16;
    #pragma unroll
    for (int j = 0; j < 4; ++j) {
      *(float4*)&wgtb[base + j * 4] =
          make_float4(e[j*4] * inv, e[j*4+1] * inv, e[j*4+2] * inv, e[j*4+3] * inv);
      *(int4*)&indb[base + j * 4] = make_int4(tix[j*4], tix[j*4+1], tix[j*4+2], tix[j*4+3]);
    }
  }
}

// ---------------------------------------------------------------------------
// fused gather + implicit-conv GEMM, XCD-swizzled.
// grid 576 (1D), 512 threads (8 waves x 2 rows).  16x16 px tile, 18x18 halo.
// A+B double-buffered in LDS -> ONE barrier per kd (16 total): stage(kd+1)
// into buf[n^1] overlaps MFMA(kd) on buf[n].  Rows stride 32 bf16 with
// chunk-XOR swizzle (chunk c of row p at c^(p&3)): 16B-aligned b128 ops at
// the 8-accesses/bank wave floor.  Gather prefetch 2-deep (vr0/vr1).
// ---------------------------------------------------------------------------
#define STAGE_A(BUF, VR, WC) do {                                              \
  if (gact) {                                                                  \
    __bf16 tmp_[32];                                                           \
    _Pragma("unroll")                                                          \
    for (int wv_ = 0; wv_ < 4; ++wv_) {                                        \
      unsigned uu_[4] = {(unsigned)VR[wv_].x, (unsigned)VR[wv_].y,             \
                         (unsigned)VR[wv_].z, (unsigned)VR[wv_].w};            \
      _Pragma("unroll")                                                        \
      for (int j2_ = 0; j2_ < 4; ++j2_) {                                      \
        float lo_ = __uint_as_float(uu_[j2_] << 16);                           \
        float hi_ = __uint_as_float(uu_[j2_] & 0xffff0000u);                   \
        tmp_[wv_ * 8 + j2_ * 2]     = (__bf16)(lo_ * (WC));                    \
        tmp_[wv_ * 8 + j2_ * 2 + 1] = (__bf16)(hi_ * (WC));                    \
      }                                                                        \
    }                                                                          \
    __bf16* dst_ = &(BUF)[tid * 32];                                           \
    *(int4*)&dst_[(0 ^ (tid & 3)) << 3] = *(const int4*)&tmp_[0];              \
    *(int4*)&dst_[(1 ^ (tid & 3)) << 3] = *(const int4*)&tmp_[8];              \
    *(int4*)&dst_[(2 ^ (tid & 3)) << 3] = *(const int4*)&tmp_[16];             \
    *(int4*)&dst_[(3 ^ (tid & 3)) << 3] = *(const int4*)&tmp_[24];             \
  }                                                                            \
} while (0)

#define STAGE_B(BUF, KD) do {                                                  \
  const __bf16* __restrict__ bsrc_ = pwt + (size_t)(g * 16 + (KD)) * 9216;     \
  _Pragma("unroll")                                                            \
  for (int itb_ = 0; itb_ < 3; ++itb_) {                                       \
    int i_ = itb_ * 512 + tid;                                                 \
    if (i_ < 1152) {                                                           \
      int row_ = i_ >> 2, c_ = i_ & 3;                                         \
      *(int4*)&(BUF)[row_ * 32 + ((c_ ^ (row_ & 3)) << 3)] =                   \
          *(const int4*)&bsrc_[row_ * 32 + c_ * 8];                            \
    }                                                                          \
  }                                                                            \
} while (0)

#define GATHER(VR, WC, IND, W) do {                                            \
  int ind_ = (IND);                                                            \
  VR[0] = VR[1] = VR[2] = VR[3] = make_int4(0, 0, 0, 0);                       \
  if (inb) {                                                                   \
    int ny_ = gy + ind_ / 7 - 3, nx_ = gx + ind_ % 7 - 3;                      \
    if ((unsigned)ny_ < 96u && (unsigned)nx_ < 96u) {                          \
      const int4* __restrict__ vp_ =                                           \
          (const int4*)(vbase + (size_t)(ny_ * 96 + nx_) * 32);                \
      VR[0] = vp_[0]; VR[1] = vp_[1]; VR[2] = vp_[2]; VR[3] = vp_[3];          \
    }                                                                          \
  }                                                                            \
  WC = (W);                                                                    \
} while (0)

#define MFMA_PHASE(AB, BB) do {                                                \
  _Pragma("unroll")                                                            \
  for (int dx2_ = 0; dx2_ < 3; ++dx2_) {                                       \
    bf16x8 a_[4];                                                              \
    _Pragma("unroll")                                                          \
    for (int r_ = 0; r_ < 4; ++r_) {                                           \
      int p_ = (wid * 2 + r_) * 18 + lr + dx2_;                                \
      a_[r_] = *(const bf16x8*)&(AB)[p_ * 32 + ((kg ^ (p_ & 3)) << 3)];        \
    }                                                                          \
    _Pragma("unroll")                                                          \
    for (int dy2_ = 0; dy2_ < 3; ++dy2_) {                                     \
      int d_ = dy2_ * 3 + dx2_;                                                \
      bf16x8 b0_ = *(const bf16x8*)&(BB)[(d_ * 32 + lr) * 32 + bswz];          \
      bf16x8 b1_ = *(const bf16x8*)&(BB)[(d_ * 32 + 16 + lr) * 32 + bswz];     \
      acc[0][0] = __builtin_amdgcn_mfma_f32_16x16x32_bf16(a_[dy2_],     b0_, acc[0][0], 0, 0, 0); \
      acc[0][1] = __builtin_amdgcn_mfma_f32_16x16x32_bf16(a_[dy2_],     b1_, acc[0][1], 0, 0, 0); \
      acc[1][0] = __builtin_amdgcn_mfma_f32_16x16x32_bf16(a_[dy2_ + 1], b0_, acc[1][0], 0, 0, 0); \
      acc[1][1] = __builtin_amdgcn_mfma_f32_16x16x32_bf16(a_[dy2_ + 1], b1_, acc[1][1], 0, 0, 0); \
    }                                                                          \
  }                                                                            \
} while (0)

__global__ __launch_bounds__(512) void proj_kernel(
    const __bf16* __restrict__ vb, const float* __restrict__ wgtb, const int* __restrict__ indb,
    const __bf16* __restrict__ pwt, const float* __restrict__ pb, float* __restrict__ outp) {
  __shared__ __align__(16) __bf16 Albuf[2][324 * 32];   // 2 x 20736 B
  __shared__ __align__(16) __bf16 Blbuf[2][288 * 32];   // 2 x 18432 B
  int tid = threadIdx.x;
  int bid = blockIdx.x;
  int wg = (bid & 7) * 72 + (bid >> 3);   // XCD-contiguous remap (576 = 8*72)
  int th = wg / 36;                        // f*4+g
  int tile = wg % 36;
  int g = th & 3;
  int ty0 = (tile / 6) * 16, tx0 = (tile % 6) * 16;
  int lane = tid & 63, wid = tid >> 6;     // wid 0..7
  int kg = lane >> 4, lr = lane & 15;
  int bswz = (kg ^ (lr & 3)) << 3;         // B-read chunk offset (lane-const)

  bool gact = tid < 324;
  int ry = tid / 18, rx = tid % 18;
  int gy = ty0 - 1 + ry, gx = tx0 - 1 + rx;
  bool inb = gact && (unsigned)gy < 96u && (unsigned)gx < 96u;
  const __bf16* __restrict__ vbase = vb + (size_t)th * 9216 * 32;
  size_t pxoff = inb ? (size_t)(gy * 96 + gx) : 0;
  const int*   __restrict__ ibase = indb + ((size_t)th * 9216 + pxoff) * 16;
  const float* __restrict__ wbase = wgtb + ((size_t)th * 9216 + pxoff) * 16;

  f32x4 acc[2][2];
  acc[0][0] = (f32x4)(0.0f); acc[0][1] = (f32x4)(0.0f);
  acc[1][0] = (f32x4)(0.0f); acc[1][1] = (f32x4)(0.0f);

  int4 iw_i = make_int4(0, 0, 0, 0);
  float4 iw_w = make_float4(0.f, 0.f, 0.f, 0.f);
  int4 vr0[4], vr1[4];
  float wc0 = 0.f, wc1 = 0.f;

  // prologue: iw block 0; gather kd0 -> stage buf0; gather kd1 -> vr1
  if (inb) {
    iw_i = *(const int4*)&ibase[0];
    iw_w = *(const float4*)&wbase[0];
  }
  GATHER(vr0, wc0, iw_i.x, iw_w.x);     // kd 0
  STAGE_A(Albuf[0], vr0, wc0);
  STAGE_B(Blbuf[0], 0);
  GATHER(vr1, wc1, iw_i.y, iw_w.y);     // kd 1
  __syncthreads();

  #pragma unroll 1
  for (int kq = 0; kq < 4; ++kq) {
    int k4 = kq * 4;
    // kd = k4+0 (reads buf0): stage kd+1 -> buf1; gather kd+2 (comp2)
    STAGE_A(Albuf[1], vr1, wc1);
    STAGE_B(Blbuf[1], k4 + 1);
    GATHER(vr0, wc0, iw_i.z, iw_w.z);
    MFMA_PHASE(Albuf[0], Blbuf[0]);
    __syncthreads();
    // kd = k4+1 (reads buf1): stage kd+1 -> buf0; gather kd+2 (comp3)
    STAGE_A(Albuf[0], vr0, wc0);
    STAGE_B(Blbuf[0], k4 + 2);
    GATHER(vr1, wc1, iw_i.w, iw_w.w);
    MFMA_PHASE(Albuf[1], Blbuf[1]);
    __syncthreads();
    // kd = k4+2 (reads buf0): stage kd+1 -> buf1; load next iw block; gather comp0
    STAGE_A(Albuf[1], vr1, wc1);
    STAGE_B(Blbuf[1], k4 + 3);
    if (kq < 3) {
      if (inb) {
        iw_i = *(const int4*)&ibase[k4 + 4];
        iw_w = *(const float4*)&wbase[k4 + 4];
      }
      GATHER(vr0, wc0, iw_i.x, iw_w.x);
    }
    MFMA_PHASE(Albuf[0], Blbuf[0]);
    __syncthreads();
    // kd = k4+3 (reads buf1): stage kd+1 -> buf0 (if exists); gather comp1
    if (kq < 3) {
      STAGE_A(Albuf[0], vr0, wc0);
      STAGE_B(Blbuf[0], k4 + 4);
      GATHER(vr1, wc1, iw_i.y, iw_w.y);
    }
    MFMA_PHASE(Albuf[1], Blbuf[1]);
    __syncthreads();
  }

  // epilogue: D col = lane&15 -> o, D row = kg*4+j -> pixel x
  int x0 = tx0 + kg * 4;
  int f = th >> 2;
  #pragma unroll
  for (int mt = 0; mt < 2; ++mt) {
    int y = ty0 + wid * 2 + mt;
    #pragma unroll
    for (int nt = 0; nt < 2; ++nt) {
      int o = g * 32 + nt * 16 + lr;
      float bias = pb[o];
      float4 res = make_float4(acc[mt][nt][0] + bias, acc[mt][nt][1] + bias,
                               acc[mt][nt][2] + bias, acc[mt][nt][3] + bias);
      *(float4*)&outp[(size_t)(f * 128 + o) * 9216 + y * 96 + x0] = res;
    }
  }
}

// ---------------------------------------------------------------------------
extern "C" void kernel_launch(void* const* d_in, const int* in_sizes, int n_in,
                              void* d_out, int out_size, void* d_ws, size_t ws_size,
                              hipStream_t stream) {
  const float* vid = (const float*)d_in[0];
  const float* lnw = (const float*)d_in[1];
  const float* lnb = (const float*)d_in[2];
  const float* wq  = (const float*)d_in[3];
  const float* bq  = (const float*)d_in[4];
  const float* wk  = (const float*)d_in[5];
  const float* bk  = (const float*)d_in[6];
  const float* wv_ = (const float*)d_in[7];
  const float* bv  = (const float*)d_in[8];
  const float* pw  = (const float*)d_in[9];
  const float* pb  = (const float*)d_in[10];
  float* outp = (float*)d_out;

  const size_t SZ_T  = (size_t)16 * 9216 * 32 * 4;     // q/k fp32 each
  const size_t SZ_TB = (size_t)16 * 9216 * 32 * 2;     // v bf16
  const size_t SZ_W  = (size_t)16 * 9216 * 16 * 4;     // wgt / ind
  const size_t SZ_WT = 128 * 384 * 4;
  const size_t SZ_PW = (size_t)4 * 16 * 9 * 32 * 32 * 2;
  const size_t SZ_MU = (size_t)4 * 9216 * 4;

  char* p = (char*)d_ws;
  float* qb = (float*)p;        p += SZ_T;
  float* kb = (float*)p;        p += SZ_T;
  __bf16* vbbf = (__bf16*)p;    p += SZ_TB;
  float* wgtb = (float*)p;      p += SZ_W;
  int*   indb = (int*)p;        p += SZ_W;
  float* Wt = (float*)p;        p += SZ_WT;
  __bf16* pwt = (__bf16*)p;     p += SZ_PW;
  float* mu = (float*)p;        p += SZ_MU;
  float* rs = (float*)p;

  prep_kernel<<<2496, 256, 0, stream>>>(wq, wk, wv_, pw, Wt, pwt);
  ln_stats_kernel<<<dim3(144, 4), 64, 0, stream>>>(vid, mu, rs);
  qkv_gemm_kernel<<<dim3(3, 288), 512, 0, stream>>>(vid, mu, rs, lnw, lnb, Wt, bq, bk, bv,
                                                    qb, kb, vbbf);
  search_kernel<<<dim3(49, 16), 256, 0, stream>>>(qb, kb, wgtb, indb);
  proj_kernel<<<576, 512, 0, stream>>>(vbbf, wgtb, indb, pwt, pb, outp);
}

// Round 12
// 209.920 us; speedup vs baseline: 1.2470x; 1.0781x over previous
//
#include <hip/hip_runtime.h>

// NonLocalAttentionStack on MI355X.
// Dims: B=1, T=4, C=128, H=W=96, NHEADS=4 (c=32/head), WS=7 (49 cands), PS=3, K=16.
// Pipeline: prep -> ln_stats -> QKV (fp32 GEMM; v output bf16) ->
//           search+topk+softmax (fp32, 16x16 tile, rolling k-band, batched-7dx
//           rounds: 2 barriers/dy) ->
//           fused gather+implicit-conv MFMA GEMM (XCD-swizzled, LDS dbuf,
//           row-pair chunk-XOR swizzle (p>>1)&3: b128 at bank floor).

typedef float  f32x4  __attribute__((ext_vector_type(4)));
typedef __bf16 bf16x8 __attribute__((ext_vector_type(8)));
typedef __bf16 bf16x4 __attribute__((ext_vector_type(4)));

__device__ __forceinline__ float dpp_shr1(float x) {  // lane L gets lane L-1 (16-lane rows)
  return __int_as_float(__builtin_amdgcn_update_dpp(0, __float_as_int(x), 0x111, 0xf, 0xf, false));
}
__device__ __forceinline__ float dpp_shl1(float x) {  // lane L gets lane L+1
  return __int_as_float(__builtin_amdgcn_update_dpp(0, __float_as_int(x), 0x101, 0xf, 0xf, false));
}

// ---------------------------------------------------------------------------
// prep: Wt[c][o=384] = {wq|wk|wv}[o][c];  pwt[g][kd][d=9][o=32][i=32] bf16
// ---------------------------------------------------------------------------
__global__ __launch_bounds__(256) void prep_kernel(
    const float* __restrict__ wq, const float* __restrict__ wk, const float* __restrict__ wv,
    const float* __restrict__ pw, float* __restrict__ Wt, __bf16* __restrict__ pwt) {
  int idx = blockIdx.x * 256 + threadIdx.x;
  const int NPW = 4 * 16 * 9 * 32 * 32;  // 589824
  if (idx < NPW) {
    int i  = idx & 31;
    int ol = (idx >> 5) & 31;
    int d  = (idx >> 10) % 9;
    int r  = (idx >> 10) / 9;   // g*16+kd
    int kd = r & 15;
    int g  = r >> 4;
    int o  = g * 32 + ol;
    pwt[idx] = (__bf16)pw[((o * 32 + i) * 16 + kd) * 9 + d];
  } else {
    int widx = idx - NPW;
    if (widx < 128 * 384) {
      int o = widx % 384;
      int c = widx / 384;
      const float* __restrict__ src = (o < 128) ? wq : (o < 256 ? wk : wv);
      Wt[widx] = src[(o & 127) * 128 + c];
    }
  }
}

// ---------------------------------------------------------------------------
// LN stats: per-pixel mean / rsqrt(var+eps).  grid (144,4) x 64 threads.
// ---------------------------------------------------------------------------
__global__ __launch_bounds__(64) void ln_stats_kernel(
    const float* __restrict__ vid, float* __restrict__ mu, float* __restrict__ rs) {
  int pix = blockIdx.x * 64 + threadIdx.x;
  int f = blockIdx.y;
  const float* __restrict__ vp = vid + (size_t)f * 128 * 9216 + pix;
  float s = 0.f, s2 = 0.f;
  #pragma unroll 8
  for (int c = 0; c < 128; ++c) { float x = vp[(size_t)c * 9216]; s += x; s2 += x * x; }
  float m_ = s * (1.f / 128.f);
  float v_ = fmaxf(s2 * (1.f / 128.f) - m_ * m_, 0.f);
  mu[f * 9216 + pix] = m_;
  rs[f * 9216 + pix] = rsqrtf(v_ + 1e-6f);
}

// ---------------------------------------------------------------------------
// QKV GEMM: 128x128 tile, K=128 in 4x32 chunks, 512 threads (8 waves),
// register double-buffered staging.  grid (3, 288); blockIdx.x selects q/k/v.
// q,k: fp32 [t*4+head][pix][c32].  v: bf16 same layout.
// ---------------------------------------------------------------------------
__global__ __launch_bounds__(512) void qkv_gemm_kernel(
    const float* __restrict__ vid, const float* __restrict__ mu, const float* __restrict__ rs,
    const float* __restrict__ lnw, const float* __restrict__ lnb,
    const float* __restrict__ Wt, const float* __restrict__ bq, const float* __restrict__ bk,
    const float* __restrict__ bv, float* __restrict__ qb, float* __restrict__ kb,
    __bf16* __restrict__ vbbf) {
  __shared__ __align__(16) float Xs[32][128];
  __shared__ __align__(16) float Ws[32][128];
  __shared__ float muL[128], rsL[128], lwS[128], lbS[128];
  int tid = threadIdx.x;
  int mt = blockIdx.y;
  int N0 = blockIdx.x * 128;
  int f  = mt / 72;
  int pf = (mt % 72) * 128;

  if (tid < 128) {
    muL[tid] = mu[f * 9216 + pf + tid];
    rsL[tid] = rs[f * 9216 + pf + tid];
  } else if (tid < 256) {
    int t2 = tid - 128;
    lwS[t2] = lnw[t2];
    lbS[t2] = lnb[t2];
  }

  int tx = tid & 15, ty = tid >> 4;   // ty 0..31
  int m0 = ty * 4;
  int sm = tid & 127;                  // staging column
  int sk = tid >> 7;                   // staging row base (0..3)
  float acc[4][8];
  #pragma unroll
  for (int a = 0; a < 4; ++a)
    #pragma unroll
    for (int b = 0; b < 8; ++b) acc[a][b] = 0.f;

  const size_t vbase = (size_t)f * 128 * 9216 + pf;
  float xr[8], wr[8];

  #pragma unroll
  for (int it = 0; it < 8; ++it) {
    int kk = sk + 4 * it;
    xr[it] = vid[vbase + (size_t)kk * 9216 + sm];
    wr[it] = Wt[(size_t)kk * 384 + N0 + sm];
  }
  __syncthreads();
  #pragma unroll
  for (int it = 0; it < 8; ++it) {
    int kk = sk + 4 * it;
    Xs[kk][sm] = (xr[it] - muL[sm]) * rsL[sm] * lwS[kk] + lbS[kk];
    Ws[kk][sm] = wr[it];
  }
  __syncthreads();

  for (int kc = 0; kc < 4; ++kc) {
    if (kc < 3) {
      #pragma unroll
      for (int it = 0; it < 8; ++it) {
        int kk = sk + 4 * it;
        int c = (kc + 1) * 32 + kk;
        xr[it] = vid[vbase + (size_t)c * 9216 + sm];
        wr[it] = Wt[(size_t)c * 384 + N0 + sm];
      }
    }
    #pragma unroll 4
    for (int kk = 0; kk < 32; ++kk) {
      float xa[4], wa[8];
      *(float4*)&xa[0] = *(const float4*)&Xs[kk][m0];
      *(float4*)&wa[0] = *(const float4*)&Ws[kk][tx * 4];
      *(float4*)&wa[4] = *(const float4*)&Ws[kk][64 + tx * 4];
      #pragma unroll
      for (int a = 0; a < 4; ++a)
        #pragma unroll
        for (int b = 0; b < 8; ++b)
          acc[a][b] = fmaf(xa[a], wa[b], acc[a][b]);
    }
    if (kc < 3) {
      __syncthreads();
      #pragma unroll
      for (int it = 0; it < 8; ++it) {
        int kk = sk + 4 * it;
        int c = (kc + 1) * 32 + kk;
        Xs[kk][sm] = (xr[it] - muL[sm]) * rsL[sm] * lwS[c] + lbS[c];
        Ws[kk][sm] = wr[it];
      }
      __syncthreads();
    }
  }

  int sel = blockIdx.x;
  int nlo = tx * 4, nhi = 64 + tx * 4;
  int hlo = nlo >> 5, clo = nlo & 31;
  int hhi = nhi >> 5, chi = nhi & 31;
  const float* __restrict__ bias = (sel == 0) ? bq : (sel == 1 ? bk : bv);
  float4 blo = make_float4(bias[nlo], bias[nlo + 1], bias[nlo + 2], bias[nlo + 3]);
  float4 bhi = make_float4(bias[nhi], bias[nhi + 1], bias[nhi + 2], bias[nhi + 3]);
  size_t base_lo = (size_t)(f * 4 + hlo) * 9216 * 32 + clo;
  size_t base_hi = (size_t)(f * 4 + hhi) * 9216 * 32 + chi;
  if (sel < 2) {
    float* __restrict__ dst = (sel == 0) ? qb : kb;
    #pragma unroll
    for (int a = 0; a < 4; ++a) {
      size_t poff = (size_t)(pf + m0 + a) * 32;
      *(float4*)&dst[base_lo + poff] = make_float4(acc[a][0] + blo.x, acc[a][1] + blo.y,
                                                   acc[a][2] + blo.z, acc[a][3] + blo.w);
      *(float4*)&dst[base_hi + poff] = make_float4(acc[a][4] + bhi.x, acc[a][5] + bhi.y,
                                                   acc[a][6] + bhi.z, acc[a][7] + bhi.w);
    }
  } else {
    #pragma unroll
    for (int a = 0; a < 4; ++a) {
      size_t poff = (size_t)(pf + m0 + a) * 32;
      bf16x4 lo4, hi4;
      lo4[0] = (__bf16)(acc[a][0] + blo.x); lo4[1] = (__bf16)(acc[a][1] + blo.y);
      lo4[2] = (__bf16)(acc[a][2] + blo.z); lo4[3] = (__bf16)(acc[a][3] + blo.w);
      hi4[0] = (__bf16)(acc[a][4] + bhi.x); hi4[1] = (__bf16)(acc[a][5] + bhi.y);
      hi4[2] = (__bf16)(acc[a][6] + bhi.z); hi4[3] = (__bf16)(acc[a][7] + bhi.w);
      *(bf16x4*)&vbbf[base_lo + poff] = lo4;
      *(bf16x4*)&vbbf[base_hi + poff] = hi4;
    }
  }
}

// ---------------------------------------------------------------------------
// search + topk + softmax.  16x16 s-region tile (inner 14x14 queries).
// Batched inner loop: per dy, all 7 dx dots computed back-to-back (56
// independent klds b128 reads pipeline), published to slds[7][256] in one
// round -> 2 barriers per dy (stage + publish) instead of 8.  Single slds
// buffer is race-free: all R(dy) precede the stage barrier of dy+1 in
// program order, which precedes W(dy+1).
// grid (49, 16), 256 threads, 3 blocks/CU (52.3 KB LDS).
// ---------------------------------------------------------------------------
__global__ __launch_bounds__(256, 3) void search_kernel(
    const float* __restrict__ qb, const float* __restrict__ kb,
    float* __restrict__ wgtb, int* __restrict__ indb) {
  __shared__ __align__(16) float klds[16 * 22 * 32];   // 45056 B
  __shared__ float slds[7][256];                        // 7168 B
  int tid = threadIdx.x;
  int th = blockIdx.y;
  int tile = blockIdx.x;
  int iy0 = (tile / 7) * 14, ix0 = (tile % 7) * 14;
  const float* __restrict__ kbase = kb + (size_t)th * 9216 * 32;

  #pragma unroll
  for (int it = 0; it < 11; ++it) {
    int i = it * 256 + tid;
    int r = i / 176, rem = i % 176;
    int col = rem >> 3, c4 = rem & 7;
    int gy = iy0 - 4 + r, gx = ix0 - 4 + col;
    float4 val = make_float4(0.f, 0.f, 0.f, 0.f);
    if ((unsigned)gy < 96u && (unsigned)gx < 96u)
      val = *(const float4*)&kbase[(size_t)(gy * 96 + gx) * 32 + c4 * 4];
    int p = r * 22 + col;
    *(float4*)&klds[p * 32 + ((c4 ^ (p & 7)) << 2)] = val;
  }

  int sy = tid >> 4, sx = tid & 15;
  int qy = iy0 - 1 + sy, qx = ix0 - 1 + sx;
  bool qok = (unsigned)qy < 96u && (unsigned)qx < 96u;
  float4 qv[8];
  #pragma unroll
  for (int j = 0; j < 8; ++j) qv[j] = make_float4(0.f, 0.f, 0.f, 0.f);
  if (qok) {
    const float* __restrict__ qp = qb + ((size_t)th * 9216 + qy * 96 + qx) * 32;
    #pragma unroll
    for (int j = 0; j < 8; ++j) qv[j] = *(const float4*)&qp[j * 4];
  }
  bool inner = (sy >= 1) && (sy <= 14) && (sx >= 1) && (sx <= 14) && qok;

  float tv[16]; int tix[16];
  #pragma unroll
  for (int j = 0; j < 16; ++j) { tv[j] = -3.0e38f; tix[j] = 0; }
  __syncthreads();

  #pragma unroll 1
  for (int dy = 0; dy < 7; ++dy) {
    if (dy > 0) {
      // stage k-region row dy+15 into slot dy-1 (all R of that slot were in
      // rounds <= dy-1, fenced by this barrier chain)
      if (tid < 176) {
        int col = tid >> 3, c4 = tid & 7;
        int r = dy + 15;
        int gy = iy0 - 4 + r, gx = ix0 - 4 + col;
        float4 val = make_float4(0.f, 0.f, 0.f, 0.f);
        if ((unsigned)gy < 96u && (unsigned)gx < 96u)
          val = *(const float4*)&kbase[(size_t)(gy * 96 + gx) * 32 + c4 * 4];
        int p = (r & 15) * 22 + col;
        *(float4*)&klds[p * 32 + ((c4 ^ (p & 7)) << 2)] = val;
      }
      __syncthreads();
    }
    // all 7 dx dots, h-sum via DPP, publish
    float h[7];
    #pragma unroll
    for (int dx = 0; dx < 7; ++dx) {
      int p = ((sy + dy) & 15) * 22 + (sx + dx);
      const float* __restrict__ kp = &klds[p * 32];
      int sw = p & 7;
      float sdot = 0.f;
      #pragma unroll
      for (int j = 0; j < 8; ++j) {
        float4 kq = *(const float4*)&kp[(j ^ sw) << 2];
        sdot += qv[j].x * kq.x + qv[j].y * kq.y + qv[j].z * kq.z + qv[j].w * kq.w;
      }
      h[dx] = sdot + dpp_shr1(sdot) + dpp_shl1(sdot);
      slds[dx][tid] = h[dx];
    }
    __syncthreads();
    if (inner) {
      #pragma unroll
      for (int dx = 0; dx < 7; ++dx) {
        float sc = h[dx] + slds[dx][tid - 16] + slds[dx][tid + 16];
        int oi = dy * 7 + dx;
        float cv = sc; int ci = oi;
        #pragma unroll
        for (int j = 0; j < 16; ++j) {
          bool gt = cv > tv[j];
          float mx = fmaxf(tv[j], cv);
          float mn = fminf(tv[j], cv);
          int nt = gt ? ci : tix[j];
          ci = gt ? tix[j] : ci;
          tv[j] = mx; cv = mn; tix[j] = nt;
        }
      }
    }
  }

  if (inner) {
    float mx = tv[0];
    float e[16], ssum = 0.f;
    #pragma unroll
    for (int j = 0; j < 16; ++j) { e[j] = __expf(tv[j] - mx); ssum += e[j]; }
    float inv = 1.f / ssum;
    size_t base = ((size_t)th * 9216 + qy * 96 + qx) * 16;
    #pragma unroll
    for (int j = 0; j < 4; ++j) {
      *(float4*)&wgtb[base + j * 4] =
          make_float4(e[j*4] * inv, e[j*4+1] * inv, e[j*4+2] * inv, e[j*4+3] * inv);
      *(int4*)&indb[base + j * 4] = make_int4(tix[j*4], tix[j*4+1], tix[j*4+2], tix[j*4+3]);
    }
  }
}

// ---------------------------------------------------------------------------
// fused gather + implicit-conv GEMM, XCD-swizzled.
// grid 576 (1D), 512 threads (8 waves x 2 rows).  16x16 px tile, 18x18 halo.
// A+B double-buffered in LDS -> ONE barrier per kd.  Rows stride 32 bf16,
// ROW-PAIR chunk-XOR swizzle (chunk c of row p at c^((p>>1)&3)): banks
// repeat every 2 rows (64B), so the pair index must drive the spread —
// every b128 read/write lands at the 8-accesses/bank wave floor.
// ---------------------------------------------------------------------------
#define STAGE_A(BUF, VR, WC) do {                                              \
  if (gact) {                                                                  \
    __bf16 tmp_[32];                                                           \
    _Pragma("unroll")                                                          \
    for (int wv_ = 0; wv_ < 4; ++wv_) {                                        \
      unsigned uu_[4] = {(unsigned)VR[wv_].x, (unsigned)VR[wv_].y,             \
                         (unsigned)VR[wv_].z, (unsigned)VR[wv_].w};            \
      _Pragma("unroll")                                                        \
      for (int j2_ = 0; j2_ < 4; ++j2_) {                                      \
        float lo_ = __uint_as_float(uu_[j2_] << 16);                           \
        float hi_ = __uint_as_float(uu_[j2_] & 0xffff0000u);                   \
        tmp_[wv_ * 8 + j2_ * 2]     = (__bf16)(lo_ * (WC));                    \
        tmp_[wv_ * 8 + j2_ * 2 + 1] = (__bf16)(hi_ * (WC));                    \
      }                                                                        \
    }                                                                          \
    __bf16* dst_ = &(BUF)[tid * 32];                                           \
    int sela_ = (tid >> 1) & 3;                                                \
    *(int4*)&dst_[(0 ^ sela_) << 3] = *(const int4*)&tmp_[0];                  \
    *(int4*)&dst_[(1 ^ sela_) << 3] = *(const int4*)&tmp_[8];                  \
    *(int4*)&dst_[(2 ^ sela_) << 3] = *(const int4*)&tmp_[16];                 \
    *(int4*)&dst_[(3 ^ sela_) << 3] = *(const int4*)&tmp_[24];                 \
  }                                                                            \
} while (0)

#define STAGE_B(BUF, KD) do {                                                  \
  const __bf16* __restrict__ bsrc_ = pwt + (size_t)(g * 16 + (KD)) * 9216;     \
  _Pragma("unroll")                                                            \
  for (int itb_ = 0; itb_ < 3; ++itb_) {                                       \
    int i_ = itb_ * 512 + tid;                                                 \
    if (i_ < 1152) {                                                           \
      int row_ = i_ >> 2, c_ = i_ & 3;                                         \
      *(int4*)&(BUF)[row_ * 32 + ((c_ ^ ((row_ >> 1) & 3)) << 3)] =            \
          *(const int4*)&bsrc_[row_ * 32 + c_ * 8];                            \
    }                                                                          \
  }                                                                            \
} while (0)

#define GATHER(VR, WC, IND, W) do {                                            \
  int ind_ = (IND);                                                            \
  VR[0] = VR[1] = VR[2] = VR[3] = make_int4(0, 0, 0, 0);                       \
  if (inb) {                                                                   \
    int ny_ = gy + ind_ / 7 - 3, nx_ = gx + ind_ % 7 - 3;                      \
    if ((unsigned)ny_ < 96u && (unsigned)nx_ < 96u) {                          \
      const int4* __restrict__ vp_ =                                           \
          (const int4*)(vbase + (size_t)(ny_ * 96 + nx_) * 32);                \
      VR[0] = vp_[0]; VR[1] = vp_[1]; VR[2] = vp_[2]; VR[3] = vp_[3];          \
    }                                                                          \
  }                                                                            \
  WC = (W);                                                                    \
} while (0)

#define MFMA_PHASE(AB, BB) do {                                                \
  _Pragma("unroll")                                                            \
  for (int dx2_ = 0; dx2_ < 3; ++dx2_) {                                       \
    bf16x8 a_[4];                                                              \
    _Pragma("unroll")                                                          \
    for (int r_ = 0; r_ < 4; ++r_) {                                           \
      int p_ = (wid * 2 + r_) * 18 + lr + dx2_;                                \
      a_[r_] = *(const bf16x8*)&(AB)[p_ * 32 + ((kg ^ ((p_ >> 1) & 3)) << 3)]; \
    }                                                                          \
    _Pragma("unroll")                                                          \
    for (int dy2_ = 0; dy2_ < 3; ++dy2_) {                                     \
      int d_ = dy2_ * 3 + dx2_;                                                \
      bf16x8 b0_ = *(const bf16x8*)&(BB)[(d_ * 32 + lr) * 32 + bswz];          \
      bf16x8 b1_ = *(const bf16x8*)&(BB)[(d_ * 32 + 16 + lr) * 32 + bswz];     \
      acc[0][0] = __builtin_amdgcn_mfma_f32_16x16x32_bf16(a_[dy2_],     b0_, acc[0][0], 0, 0, 0); \
      acc[0][1] = __builtin_amdgcn_mfma_f32_16x16x32_bf16(a_[dy2_],     b1_, acc[0][1], 0, 0, 0); \
      acc[1][0] = __builtin_amdgcn_mfma_f32_16x16x32_bf16(a_[dy2_ + 1], b0_, acc[1][0], 0, 0, 0); \
      acc[1][1] = __builtin_amdgcn_mfma_f32_16x16x32_bf16(a_[dy2_ + 1], b1_, acc[1][1], 0, 0, 0); \
    }                                                                          \
  }                                                                            \
} while (0)

__global__ __launch_bounds__(512) void proj_kernel(
    const __bf16* __restrict__ vb, const float* __restrict__ wgtb, const int* __restrict__ indb,
    const __bf16* __restrict__ pwt, const float* __restrict__ pb, float* __restrict__ outp) {
  __shared__ __align__(16) __bf16 Albuf[2][324 * 32];   // 2 x 20736 B
  __shared__ __align__(16) __bf16 Blbuf[2][288 * 32];   // 2 x 18432 B
  int tid = threadIdx.x;
  int bid = blockIdx.x;
  int wg = (bid & 7) * 72 + (bid >> 3);   // XCD-contiguous remap (576 = 8*72)
  int th = wg / 36;                        // f*4+g
  int tile = wg % 36;
  int g = th & 3;
  int ty0 = (tile / 6) * 16, tx0 = (tile % 6) * 16;
  int lane = tid & 63, wid = tid >> 6;     // wid 0..7
  int kg = lane >> 4, lr = lane & 15;
  int bswz = (kg ^ ((lr >> 1) & 3)) << 3;  // B-read chunk offset (lane-const)

  bool gact = tid < 324;
  int ry = tid / 18, rx = tid % 18;
  int gy = ty0 - 1 + ry, gx = tx0 - 1 + rx;
  bool inb = gact && (unsigned)gy < 96u && (unsigned)gx < 96u;
  const __bf16* __restrict__ vbase = vb + (size_t)th * 9216 * 32;
  size_t pxoff = inb ? (size_t)(gy * 96 + gx) : 0;
  const int*   __restrict__ ibase = indb + ((size_t)th * 9216 + pxoff) * 16;
  const float* __restrict__ wbase = wgtb + ((size_t)th * 9216 + pxoff) * 16;

  f32x4 acc[2][2];
  acc[0][0] = (f32x4)(0.0f); acc[0][1] = (f32x4)(0.0f);
  acc[1][0] = (f32x4)(0.0f); acc[1][1] = (f32x4)(0.0f);

  int4 iw_i = make_int4(0, 0, 0, 0);
  float4 iw_w = make_float4(0.f, 0.f, 0.f, 0.f);
  int4 vr0[4], vr1[4];
  float wc0 = 0.f, wc1 = 0.f;

  // prologue: iw block 0; gather kd0 -> stage buf0; gather kd1 -> vr1
  if (inb) {
    iw_i = *(const int4*)&ibase[0];
    iw_w = *(const float4*)&wbase[0];
  }
  GATHER(vr0, wc0, iw_i.x, iw_w.x);     // kd 0
  STAGE_A(Albuf[0], vr0, wc0);
  STAGE_B(Blbuf[0], 0);
  GATHER(vr1, wc1, iw_i.y, iw_w.y);     // kd 1
  __syncthreads();

  #pragma unroll 1
  for (int kq = 0; kq < 4; ++kq) {
    int k4 = kq * 4;
    // kd = k4+0 (reads buf0): stage kd+1 -> buf1; gather kd+2 (comp2)
    STAGE_A(Albuf[1], vr1, wc1);
    STAGE_B(Blbuf[1], k4 + 1);
    GATHER(vr0, wc0, iw_i.z, iw_w.z);
    MFMA_PHASE(Albuf[0], Blbuf[0]);
    __syncthreads();
    // kd = k4+1 (reads buf1): stage kd+1 -> buf0; gather kd+2 (comp3)
    STAGE_A(Albuf[0], vr0, wc0);
    STAGE_B(Blbuf[0], k4 + 2);
    GATHER(vr1, wc1, iw_i.w, iw_w.w);
    MFMA_PHASE(Albuf[1], Blbuf[1]);
    __syncthreads();
    // kd = k4+2 (reads buf0): stage kd+1 -> buf1; load next iw block; gather comp0
    STAGE_A(Albuf[1], vr1, wc1);
    STAGE_B(Blbuf[1], k4 + 3);
    if (kq < 3) {
      if (inb) {
        iw_i = *(const int4*)&ibase[k4 + 4];
        iw_w = *(const float4*)&wbase[k4 + 4];
      }
      GATHER(vr0, wc0, iw_i.x, iw_w.x);
    }
    MFMA_PHASE(Albuf[0], Blbuf[0]);
    __syncthreads();
    // kd = k4+3 (reads buf1): stage kd+1 -> buf0 (if exists); gather comp1
    if (kq < 3) {
      STAGE_A(Albuf[0], vr0, wc0);
      STAGE_B(Blbuf[0], k4 + 4);
      GATHER(vr1, wc1, iw_i.y, iw_w.y);
    }
    MFMA_PHASE(Albuf[1], Blbuf[1]);
    __syncthreads();
  }

  // epilogue: D col = lane&15 -> o, D row = kg*4+j -> pixel x
  int x0 = tx0 + kg * 4;
  int f = th >> 2;
  #pragma unroll
  for (int mt = 0; mt < 2; ++mt) {
    int y = ty0 + wid * 2 + mt;
    #pragma unroll
    for (int nt = 0; nt < 2; ++nt) {
      int o = g * 32 + nt * 16 + lr;
      float bias = pb[o];
      float4 res = make_float4(acc[mt][nt][0] + bias, acc[mt][nt][1] + bias,
                               acc[mt][nt][2] + bias, acc[mt][nt][3] + bias);
      *(float4*)&outp[(size_t)(f * 128 + o) * 9216 + y * 96 + x0] = res;
    }
  }
}

// ---------------------------------------------------------------------------
extern "C" void kernel_launch(void* const* d_in, const int* in_sizes, int n_in,
                              void* d_out, int out_size, void* d_ws, size_t ws_size,
                              hipStream_t stream) {
  const float* vid = (const float*)d_in[0];
  const float* lnw = (const float*)d_in[1];
  const float* lnb = (const float*)d_in[2];
  const float* wq  = (const float*)d_in[3];
  const float* bq  = (const float*)d_in[4];
  const float* wk  = (const float*)d_in[5];
  const float* bk  = (const float*)d_in[6];
  const float* wv_ = (const float*)d_in[7];
  const float* bv  = (const float*)d_in[8];
  const float* pw  = (const float*)d_in[9];
  const float* pb  = (const float*)d_in[10];
  float* outp = (float*)d_out;

  const size_t SZ_T  = (size_t)16 * 9216 * 32 * 4;     // q/k fp32 each
  const size_t SZ_TB = (size_t)16 * 9216 * 32 * 2;     // v bf16
  const size_t SZ_W  = (size_t)16 * 9216 * 16 * 4;     // wgt / ind
  const size_t SZ_WT = 128 * 384 * 4;
  const size_t SZ_PW = (size_t)4 * 16 * 9 * 32 * 32 * 2;
  const size_t SZ_MU = (size_t)4 * 9216 * 4;

  char* p = (char*)d_ws;
  float* qb = (float*)p;        p += SZ_T;
  float* kb = (float*)p;        p += SZ_T;
  __bf16* vbbf = (__bf16*)p;    p += SZ_TB;
  float* wgtb = (float*)p;      p += SZ_W;
  int*   indb = (int*)p;        p += SZ_W;
  float* Wt = (float*)p;        p += SZ_WT;
  __bf16* pwt = (__bf16*)p;     p += SZ_PW;
  float* mu = (float*)p;        p += SZ_MU;
  float* rs = (float*)p;

  prep_kernel<<<2496, 256, 0, stream>>>(wq, wk, wv_, pw, Wt, pwt);
  ln_stats_kernel<<<dim3(144, 4), 64, 0, stream>>>(vid, mu, rs);
  qkv_gemm_kernel<<<dim3(3, 288), 512, 0, stream>>>(vid, mu, rs, lnw, lnb, Wt, bq, bk, bv,
                                                    qb, kb, vbbf);
  search_kernel<<<dim3(49, 16), 256, 0, stream>>>(qb, kb, wgtb, indb);
  proj_kernel<<<576, 512, 0, stream>>>(vbbf, wgtb, indb, pwt, pb, outp);
}